// Round 16
// baseline (501.858 us; speedup 1.0000x reference)
//
#include <hip/hip_runtime.h>
#include <hip/hip_bf16.h>
#include <cstdint>
#include <cstddef>

typedef __bf16 bf16_t;
typedef __bf16 bf16x8 __attribute__((ext_vector_type(8)));
typedef __bf16 bf16x4 __attribute__((ext_vector_type(4)));
typedef float  f32x4  __attribute__((ext_vector_type(4)));

#define B_    4
#define NQ_   2048
#define NK_   2048
#define H_    8
#define MSL_  40
#define NKP_  2112   // NK + 64 (memory slots padded)
#define SCL2  0.18033688011112042f   // 0.125 * log2(e), folded into Q projection

// ---------------------------------------------------------------------------
__global__ void detect_mask(const unsigned int* __restrict__ m, int* __restrict__ flag)
{
    __shared__ int found;
    if (threadIdx.x == 0) found = 0;
    __syncthreads();
    unsigned int acc = 0;
    for (int i = threadIdx.x; i < 65536; i += 256)
        acc |= (m[i] & 0xFFFFFF00u);
    if (acc) found = 1;
    __syncthreads();
    if (threadIdx.x == 0) *flag = found;
}

// ---------------------------------------------------------------------------
__global__ void transpose_convert4(const float* __restrict__ s0, const float* __restrict__ s1,
                                   const float* __restrict__ s2, const float* __restrict__ s3,
                                   bf16_t* __restrict__ d0, bf16_t* __restrict__ d1,
                                   bf16_t* __restrict__ d2, bf16_t* __restrict__ d3)
{
    const float* src; bf16_t* dst;
    switch (blockIdx.z) {
        case 0:  src = s0; dst = d0; break;
        case 1:  src = s1; dst = d1; break;
        case 2:  src = s2; dst = d2; break;
        default: src = s3; dst = d3; break;
    }
    __shared__ float t[32][33];
    int x  = blockIdx.x * 32 + threadIdx.x;
    int y0 = blockIdx.y * 32 + threadIdx.y;
#pragma unroll
    for (int i = 0; i < 32; i += 8)
        t[threadIdx.y + i][threadIdx.x] = src[(size_t)(y0 + i) * 512 + x];
    __syncthreads();
    int ox  = blockIdx.y * 32 + threadIdx.x;
    int oy0 = blockIdx.x * 32 + threadIdx.y;
#pragma unroll
    for (int i = 0; i < 32; i += 8)
        dst[(size_t)(oy0 + i) * 512 + ox] = (bf16_t)t[threadIdx.x][threadIdx.y + i];
}

// ---------------------------------------------------------------------------
__global__ void memfill(const float* __restrict__ m_k, const float* __restrict__ m_v,
                        bf16_t* __restrict__ Kbf, bf16_t* __restrict__ Vt)
{
    int tid = blockIdx.x * 256 + threadIdx.x;
    if (tid < 4 * 64 * 512) {
        int c  = tid & 511;
        int mi = (tid >> 9) & 63;
        int b  = tid >> 15;
        float v = (mi < MSL_) ? 8.0f * m_k[mi * 512 + c] : 0.0f;   // sqrt(DK)=8
        Kbf[((size_t)b * NKP_ + NK_ + mi) * 512 + c] = (bf16_t)v;
    } else {
        int t  = tid - 4 * 64 * 512;
        int mi = t & 63;
        int dv = (t >> 6) & 63;
        int h  = (t >> 12) & 7;
        int b  = t >> 15;
        float v = (mi < MSL_) ? 6.324555320336759f * m_v[mi * 512 + h * 64 + dv] : 0.0f; // sqrt(M)
        Vt[(((size_t)b * H_ + h) * 64 + dv) * NKP_ + NK_ + mi] = (bf16_t)v;
    }
}

// ---------------------------------------------------------------------------
// Shared GEMM core: C(8192x512) = A @ BT^T, epilogue (v+bias)*scale.
// ---------------------------------------------------------------------------
template<bool AF32>
__device__ __forceinline__ void gemm_core(
    bf16_t (*As)[72], bf16_t (*Bs)[72],
    const void* __restrict__ Av, const bf16_t* __restrict__ BT,
    const float* __restrict__ bias, void* __restrict__ dstv,
    int dstBS, int epi, float scale)
{
    const int tid = threadIdx.x;
    const int w = tid >> 6, l = tid & 63, lg = l >> 4, lr = l & 15;
    const int wr = w >> 1, wc = w & 1;
    const int blockM = blockIdx.x * 128, blockN = blockIdx.y * 128;

    f32x4 acc[4][4];
    const f32x4 zv = {0.f, 0.f, 0.f, 0.f};
#pragma unroll
    for (int i = 0; i < 4; i++)
#pragma unroll
        for (int j = 0; j < 4; j++) acc[i][j] = zv;

    const int ar = tid >> 1;
    const int ac = (tid & 1) * 32;

    for (int k0 = 0; k0 < 512; k0 += 64) {
        if (k0) __syncthreads();
        if constexpr (AF32) {
            const float* arow = (const float*)Av + (size_t)(blockM + ar) * 512 + k0 + ac;
#pragma unroll
            for (int i = 0; i < 8; i++) {
                float4 v = ((const float4*)arow)[i];
                bf16x4 pk = {(bf16_t)v.x, (bf16_t)v.y, (bf16_t)v.z, (bf16_t)v.w};
                *(bf16x4*)&As[ar][ac + i * 4] = pk;
            }
        } else {
            const bf16_t* arow = (const bf16_t*)Av + (size_t)(blockM + ar) * 512 + k0 + ac;
#pragma unroll
            for (int i = 0; i < 4; i++)
                *(uint4*)&As[ar][ac + i * 8] = ((const uint4*)arow)[i];
        }
        {
            const bf16_t* brow = BT + (size_t)(blockN + ar) * 512 + k0 + ac;
#pragma unroll
            for (int i = 0; i < 4; i++)
                *(uint4*)&Bs[ar][ac + i * 8] = ((const uint4*)brow)[i];
        }
        __syncthreads();
#pragma unroll
        for (int ks = 0; ks < 2; ks++) {
            bf16x8 af[4], bfr[4];
#pragma unroll
            for (int mi = 0; mi < 4; mi++)
                af[mi] = *(const bf16x8*)&As[wr * 64 + mi * 16 + lr][ks * 32 + lg * 8];
#pragma unroll
            for (int ni = 0; ni < 4; ni++)
                bfr[ni] = *(const bf16x8*)&Bs[wc * 64 + ni * 16 + lr][ks * 32 + lg * 8];
#pragma unroll
            for (int mi = 0; mi < 4; mi++)
#pragma unroll
                for (int ni = 0; ni < 4; ni++)
                    acc[mi][ni] = __builtin_amdgcn_mfma_f32_16x16x32_bf16(af[mi], bfr[ni], acc[mi][ni], 0, 0, 0);
        }
    }

    const int colbase = blockN + wc * 64;
    float bias_v[4];
#pragma unroll
    for (int ni = 0; ni < 4; ni++) bias_v[ni] = bias[colbase + ni * 16 + lr];

#pragma unroll
    for (int mi = 0; mi < 4; mi++) {
        const int r0 = blockM + wr * 64 + mi * 16 + lg * 4;
#pragma unroll
        for (int ni = 0; ni < 4; ni++) {
            const int c = colbase + ni * 16 + lr;
            f32x4 v = acc[mi][ni];
            if (epi == 2) {
                float* dst = (float*)dstv;
#pragma unroll
                for (int j = 0; j < 4; j++)
                    dst[(size_t)(r0 + j) * 512 + c] = (v[j] + bias_v[ni]) * scale;
            } else if (epi == 0) {
                bf16_t* dst = (bf16_t*)dstv;
#pragma unroll
                for (int j = 0; j < 4; j++) {
                    int rr = r0 + j;
                    int bb = rr >> 11, nn = rr & 2047;
                    dst[((size_t)bb * dstBS + nn) * 512 + c] = (bf16_t)((v[j] + bias_v[ni]) * scale);
                }
            } else {
                bf16_t* dst = (bf16_t*)dstv;
                int bb = r0 >> 11, n0 = r0 & 2047;
                int hh = c >> 6, dv = c & 63;
                bf16x4 pk;
#pragma unroll
                for (int j = 0; j < 4; j++) pk[j] = (bf16_t)((v[j] + bias_v[ni]) * scale);
                *(bf16x4*)(dst + (((size_t)bb * H_ + hh) * 64 + dv) * NKP_ + n0) = pk;
            }
        }
    }
}

__global__ __launch_bounds__(256) void gemm_qkv(
    const float* __restrict__ q, const float* __restrict__ k, const float* __restrict__ v,
    const bf16_t* __restrict__ WqT, const bf16_t* __restrict__ WkT, const bf16_t* __restrict__ WvT,
    const float* __restrict__ bq, const float* __restrict__ bk, const float* __restrict__ bv,
    bf16_t* __restrict__ Qbf, bf16_t* __restrict__ Kbf, bf16_t* __restrict__ Vt)
{
    __shared__ bf16_t As[128][72];
    __shared__ bf16_t Bs[128][72];
    const void* Av; const bf16_t* BT; const float* bias; void* dst;
    int dstBS, epi; float scale = 1.0f;
    switch (blockIdx.z) {
        case 0:  Av = q; BT = WqT; bias = bq; dst = Qbf; dstBS = 2048; epi = 0; scale = SCL2; break;
        case 1:  Av = k; BT = WkT; bias = bk; dst = Kbf; dstBS = NKP_; epi = 0; break;
        default: Av = v; BT = WvT; bias = bv; dst = Vt;  dstBS = 0;    epi = 1; break;
    }
    gemm_core<true>(As, Bs, Av, BT, bias, dst, dstBS, epi, scale);
}

__global__ __launch_bounds__(256) void gemm_fin(
    const bf16_t* __restrict__ Obuf, const bf16_t* __restrict__ WoT,
    const float* __restrict__ bo, float* __restrict__ out)
{
    __shared__ bf16_t As[128][72];
    __shared__ bf16_t Bs[128][72];
    gemm_core<false>(As, Bs, Obuf, WoT, bo, out, 0, 2, 1.0f);
}

// ---------------------------------------------------------------------------
// Fused attention — ZERO BARRIERS (fully wave-independent).
// R10/R15 established attn time ~ barrier-step count x convoy cost; this is
// the limit of that line: no cross-wave sharing at all. Each wave owns 16
// q-rows and streams 33 k-tiles with K/V fragments read DIRECTLY from global
// (R3-verified indexing; K/V panels are L2/L3-resident) into registers:
//   - K-frags (8x bf16x8) refilled into the same regs right after QKT
//     consumes them -> K(t+1) latency hides under softmax+PV(t).
//   - V-frags refilled right after PV consumes them (full tile of cover).
//   - attw/mask 2-deep (wA/wB alternation, refilled after APPLY).
// P-crossing LDS is WAVE-PRIVATE (Pl[wv]) — same-wave ds ordering is handled
// by the compiler's lgkmcnt; no __syncthreads anywhere. Max-free softmax
// (bounded logits, masked -> exp2(-1e30)=0, memory slots keep lsum > 0).
// 4 waves/block, grid (32,8,4); LDS 8KB; VGPR ~160 (no min-waves cap — R4).
// ---------------------------------------------------------------------------
template<bool BYTEM>
__global__ __launch_bounds__(256) void attn_fused(
    const bf16_t* __restrict__ Qbf, const bf16_t* __restrict__ Kbf,
    const bf16_t* __restrict__ Vt, const float* __restrict__ attw,
    const void* __restrict__ maskv, const int* __restrict__ mflag,
    bf16_t* __restrict__ Obuf)
{
    if ((*mflag != 0) != BYTEM) return;   // twin-variant dispatch on mask dtype

    __shared__ bf16_t Pl[4][1024];        // per-wave (PRIVATE) P crossing buf

    const int tid = threadIdx.x;
    const int wv = tid >> 6, l = tid & 63, lg = l >> 4, lr = l & 15;
    const int qt = blockIdx.x, h = blockIdx.y, b = blockIdx.z;
    const int q0w = qt * 64 + wv * 16;
    bf16_t* Pw = &Pl[wv][0];

    const size_t bh = (size_t)(b * H_ + h);
    const float* wbase = attw + bh * (size_t)NQ_ * NK_;
    const unsigned char* mb8 = (const unsigned char*)maskv + bh * (size_t)NQ_ * NK_;
    const int* mb32 = (const int*)maskv + bh * (size_t)NQ_ * NK_;
    const bf16_t* kbase = Kbf + (size_t)b * NKP_ * 512 + h * 64;
    const bf16_t* vbase = Vt + bh * 64 * (size_t)NKP_;

    // Q fragments; Q pre-scaled by 0.125*log2(e) in projection
    bf16x8 qf0 = *(const bf16x8*)&Qbf[((size_t)b * NQ_ + q0w + lr) * 512 + h * 64 + lg * 8];
    bf16x8 qf1 = *(const bf16x8*)&Qbf[((size_t)b * NQ_ + q0w + lr) * 512 + h * 64 + 32 + lg * 8];

    const f32x4 zv = {0.f, 0.f, 0.f, 0.f};
    f32x4 oacc[4];
#pragma unroll
    for (int i = 0; i < 4; i++) oacc[i] = zv;
    float lsum = 0.f;
    f32x4 sA[4];

    bf16x8 kf[8];                 // K frags for current tile (refilled in place)
    bf16x8 vf[8];                 // V frags for current tile (refilled in place)
    f32x4 wA[4], wB[4];
    unsigned mA[4], mB[4];        // byte-mask buffers
    unsigned miA[16], miB[16];    // int32-mask buffers (dead if BYTEM)

// load K frags for tile at k-base KCB into kf (8x global dwordx4, scattered)
#define KLOAD(KCB) do {                                                           \
    _Pragma("unroll") for (int n_ = 0; n_ < 4; n_++) {                            \
        const bf16_t* kp_ = kbase + (size_t)((KCB) + n_ * 16 + lr) * 512 + lg * 8;\
        kf[n_ * 2]     = *(const bf16x8*)kp_;                                     \
        kf[n_ * 2 + 1] = *(const bf16x8*)(kp_ + 32);                              \
    }                                                                             \
} while (0)

#define VLOAD(KCB) do {                                                           \
    _Pragma("unroll") for (int n_ = 0; n_ < 4; n_++) {                            \
        const bf16_t* vp_ = vbase + (size_t)(n_ * 16 + lr) * NKP_ + (KCB) + lg * 8; \
        vf[n_ * 2]     = *(const bf16x8*)vp_;                                     \
        vf[n_ * 2 + 1] = *(const bf16x8*)(vp_ + 32);                              \
    }                                                                             \
} while (0)

#define PREFETCH(KT, WB_, MB_, MIB_) do {                                         \
    const float* wp_ = wbase + (size_t)(q0w + lr) * NK_ + (KT) * 64 + lg * 4;     \
    _Pragma("unroll") for (int n_ = 0; n_ < 4; n_++)                              \
        WB_[n_] = *(const f32x4*)(wp_ + n_ * 16);                                 \
    if constexpr (BYTEM) {                                                        \
        const unsigned char* mp_ = mb8 + (size_t)(q0w + lr) * NK_ + (KT) * 64 + lg * 4; \
        _Pragma("unroll") for (int n_ = 0; n_ < 4; n_++)                          \
            MB_[n_] = *(const unsigned*)(mp_ + n_ * 16);                          \
    } else {                                                                      \
        const int* mp_ = mb32 + (size_t)(q0w + lr) * NK_ + (KT) * 64 + lg * 4;    \
        _Pragma("unroll") for (int n_ = 0; n_ < 4; n_++) {                        \
            uint4 t_ = *(const uint4*)(mp_ + n_ * 16);                            \
            MIB_[n_ * 4 + 0] = t_.x; MIB_[n_ * 4 + 1] = t_.y;                     \
            MIB_[n_ * 4 + 2] = t_.z; MIB_[n_ * 4 + 3] = t_.w; }                   \
    }                                                                             \
} while (0)

// QKT from registers (R3-verified operand order)
#define QKT_R() do {                                                              \
    _Pragma("unroll") for (int n_ = 0; n_ < 4; n_++) {                            \
        f32x4 a_ = zv;                                                            \
        a_ = __builtin_amdgcn_mfma_f32_16x16x32_bf16(kf[n_ * 2],     qf0, a_, 0, 0, 0); \
        a_ = __builtin_amdgcn_mfma_f32_16x16x32_bf16(kf[n_ * 2 + 1], qf1, a_, 0, 0, 0); \
        sA[n_] = a_;                                                              \
    }                                                                             \
} while (0)

#define APPLY(WB_, MB_, MIB_) do {                                                \
    _Pragma("unroll") for (int n_ = 0; n_ < 4; n_++)                              \
    _Pragma("unroll") for (int j_ = 0; j_ < 4; j_++) {                            \
        bool mk_;                                                                 \
        if constexpr (BYTEM) mk_ = ((MB_[n_] >> (8 * j_)) & 0xffu) != 0;          \
        else                 mk_ = (MIB_[n_ * 4 + j_] != 0);                      \
        sA[n_][j_] = mk_ ? -1e30f : sA[n_][j_] * WB_[n_][j_];                     \
    }                                                                             \
} while (0)

// max-free softmax + P crossing (wave-private LDS) + PV from registers
#define SMPV_R() do {                                                             \
    _Pragma("unroll") for (int n_ = 0; n_ < 4; n_++)                              \
    _Pragma("unroll") for (int j_ = 0; j_ < 4; j_++) {                            \
        float p_ = exp2f(sA[n_][j_]);                                             \
        sA[n_][j_] = p_; lsum += p_;                                              \
    }                                                                             \
    _Pragma("unroll") for (int n_ = 0; n_ < 4; n_++) {                            \
        int c_ = n_ * 2 + (lg >> 1);                                              \
        int qp_ = (lr + 4 * c_) & 15;                                             \
        bf16x4 pk_ = {(bf16_t)sA[n_][0], (bf16_t)sA[n_][1],                       \
                      (bf16_t)sA[n_][2], (bf16_t)sA[n_][3]};                      \
        *(bf16x4*)&Pw[c_ * 128 + qp_ * 8 + (lg & 1) * 4] = pk_;                   \
    }                                                                             \
    bf16x8 pf0_ = *(const bf16x8*)&Pw[lg * 128 + ((lr + 4 * lg) & 15) * 8];       \
    bf16x8 pf1_ = *(const bf16x8*)&Pw[(4 + lg) * 128 + ((lr + 4 * (4 + lg)) & 15) * 8]; \
    _Pragma("unroll") for (int n2_ = 0; n2_ < 4; n2_++) {                         \
        oacc[n2_] = __builtin_amdgcn_mfma_f32_16x16x32_bf16(vf[n2_ * 2],     pf0_, oacc[n2_], 0, 0, 0); \
        oacc[n2_] = __builtin_amdgcn_mfma_f32_16x16x32_bf16(vf[n2_ * 2 + 1], pf1_, oacc[n2_], 0, 0, 0); \
    }                                                                             \
} while (0)

// body for tile T: consume kf/vf/attw-regs; refill kf<-K(T+1) after QKT,
// refill attw 2 ahead after APPLY, refill vf<-V(T+1) after PV.
#define BODY(T, WC_, MC_, MIC_) do {                                              \
    QKT_R();                                                                      \
    if ((T) < 31) KLOAD(((T) + 1) * 64);                                          \
    APPLY(WC_, MC_, MIC_);                                                        \
    if ((T) < 30) PREFETCH((T) + 2, WC_, MC_, MIC_);                              \
    SMPV_R();                                                                     \
    if ((T) < 31) VLOAD(((T) + 1) * 64);                                          \
} while (0)

    // ---- prologue: memslot K/V + attw(0) ----
    KLOAD(2048);
    VLOAD(2048);
    PREFETCH(0, wA, mA, miA);

    // ---- memslot body: pad-mask; refill K<-t0, attw(1)->wB, V<-t0 ----
    {
        QKT_R();
        KLOAD(0);
#pragma unroll
        for (int n_ = 0; n_ < 4; n_++)
#pragma unroll
            for (int j_ = 0; j_ < 4; j_++) {
                int kloc = n_ * 16 + lg * 4 + j_;
                sA[n_][j_] = (kloc >= MSL_) ? -1e30f : sA[n_][j_];
            }
        PREFETCH(1, wB, mB, miB);
        SMPV_R();
        VLOAD(0);
    }

    // ---- main tiles 0..31; attw regs alternate wA/wB ----
    for (int t = 0; t < 32; t += 2) {
        BODY(t,     wA, mA, miA);
        BODY(t + 1, wB, mB, miB);
    }

    // ---- epilogue: ONE lsum reduction, then normalize + store ----
    float ts = lsum;
    ts += __shfl_xor(ts, 16);
    ts += __shfl_xor(ts, 32);
    float invl = 1.0f / ts;
#pragma unroll
    for (int n2 = 0; n2 < 4; n2++) {
        bf16x4 ov = {(bf16_t)(oacc[n2][0] * invl), (bf16_t)(oacc[n2][1] * invl),
                     (bf16_t)(oacc[n2][2] * invl), (bf16_t)(oacc[n2][3] * invl)};
        *(bf16x4*)&Obuf[((size_t)b * NQ_ + q0w + lr) * 512 + h * 64 + n2 * 16 + lg * 4] = ov;
    }

#undef KLOAD
#undef VLOAD
#undef PREFETCH
#undef QKT_R
#undef APPLY
#undef SMPV_R
#undef BODY
}

// ---------------------------------------------------------------------------
extern "C" void kernel_launch(void* const* d_in, const int* in_sizes, int n_in,
                              void* d_out, int out_size, void* d_ws, size_t ws_size,
                              hipStream_t stream)
{
    const float* queries = (const float*)d_in[0];
    const float* keys    = (const float*)d_in[1];
    const float* values  = (const float*)d_in[2];
    const float* attw    = (const float*)d_in[3];
    const void*  maskv   = d_in[4];
    const float* Wq = (const float*)d_in[5];
    const float* bq = (const float*)d_in[6];
    const float* Wk = (const float*)d_in[7];
    const float* bk = (const float*)d_in[8];
    const float* Wv = (const float*)d_in[9];
    const float* bv = (const float*)d_in[10];
    const float* Wo = (const float*)d_in[11];
    const float* bo = (const float*)d_in[12];
    const float* m_k = (const float*)d_in[13];
    const float* m_v = (const float*)d_in[14];

    char* ws = (char*)d_ws;
    bf16_t* WqT  = (bf16_t*)(ws + 0);
    bf16_t* WkT  = (bf16_t*)(ws + 524288);
    bf16_t* WvT  = (bf16_t*)(ws + 1048576);
    bf16_t* WoT  = (bf16_t*)(ws + 1572864);
    bf16_t* Qbf  = (bf16_t*)(ws + 2097152);              // [4][2048][512]
    bf16_t* Kbf  = (bf16_t*)(ws + 10485760);             // [4][2112][512]
    bf16_t* Vt   = (bf16_t*)(ws + 19136512);             // [4][8][64][2112]
    bf16_t* Obuf = (bf16_t*)(ws + 27787264);             // [4][2048][512]
    int*    mflag = (int*)(ws + 36175872);

    detect_mask<<<1, 256, 0, stream>>>((const unsigned int*)maskv, mflag);
    transpose_convert4<<<dim3(16, 16, 4), dim3(32, 8), 0, stream>>>(
        Wq, Wk, Wv, Wo, WqT, WkT, WvT, WoT);
    memfill<<<1024, 256, 0, stream>>>(m_k, m_v, Kbf, Vt);

    gemm_qkv<<<dim3(64, 4, 3), 256, 0, stream>>>(
        queries, keys, values, WqT, WkT, WvT, bq, bk, bv, Qbf, Kbf, Vt);

    attn_fused<true><<<dim3(32, H_, B_), 256, 0, stream>>>(Qbf, Kbf, Vt, attw, maskv, mflag, Obuf);
    attn_fused<false><<<dim3(32, H_, B_), 256, 0, stream>>>(Qbf, Kbf, Vt, attw, maskv, mflag, Obuf);

    gemm_fin<<<dim3(64, 4), 256, 0, stream>>>(Obuf, WoT, bo, (float*)d_out);
    (void)in_sizes; (void)n_in; (void)out_size; (void)ws_size;
}

// Round 17
// 345.610 us; speedup vs baseline: 1.4521x; 1.4521x over previous
//
#include <hip/hip_runtime.h>
#include <hip/hip_bf16.h>
#include <cstdint>
#include <cstddef>

typedef __bf16 bf16_t;
typedef __bf16 bf16x8 __attribute__((ext_vector_type(8)));
typedef __bf16 bf16x4 __attribute__((ext_vector_type(4)));
typedef float  f32x4  __attribute__((ext_vector_type(4)));

#define B_    4
#define NQ_   2048
#define NK_   2048
#define H_    8
#define MSL_  40
#define NKP_  2112   // NK + 64 (memory slots padded)
#define SCL2  0.18033688011112042f   // 0.125 * log2(e), folded into Q projection

#define GLOAD_LDS16(GP, LP)                                                        \
    __builtin_amdgcn_global_load_lds(                                              \
        (const __attribute__((address_space(1))) unsigned int*)(GP),               \
        (__attribute__((address_space(3))) unsigned int*)(LP), 16, 0, 0)

// ---------------------------------------------------------------------------
__global__ void detect_mask(const unsigned int* __restrict__ m, int* __restrict__ flag)
{
    __shared__ int found;
    if (threadIdx.x == 0) found = 0;
    __syncthreads();
    unsigned int acc = 0;
    for (int i = threadIdx.x; i < 65536; i += 256)
        acc |= (m[i] & 0xFFFFFF00u);
    if (acc) found = 1;
    __syncthreads();
    if (threadIdx.x == 0) *flag = found;
}

// ---------------------------------------------------------------------------
__global__ void transpose_convert4(const float* __restrict__ s0, const float* __restrict__ s1,
                                   const float* __restrict__ s2, const float* __restrict__ s3,
                                   bf16_t* __restrict__ d0, bf16_t* __restrict__ d1,
                                   bf16_t* __restrict__ d2, bf16_t* __restrict__ d3)
{
    const float* src; bf16_t* dst;
    switch (blockIdx.z) {
        case 0:  src = s0; dst = d0; break;
        case 1:  src = s1; dst = d1; break;
        case 2:  src = s2; dst = d2; break;
        default: src = s3; dst = d3; break;
    }
    __shared__ float t[32][33];
    int x  = blockIdx.x * 32 + threadIdx.x;
    int y0 = blockIdx.y * 32 + threadIdx.y;
#pragma unroll
    for (int i = 0; i < 32; i += 8)
        t[threadIdx.y + i][threadIdx.x] = src[(size_t)(y0 + i) * 512 + x];
    __syncthreads();
    int ox  = blockIdx.y * 32 + threadIdx.x;
    int oy0 = blockIdx.x * 32 + threadIdx.y;
#pragma unroll
    for (int i = 0; i < 32; i += 8)
        dst[(size_t)(oy0 + i) * 512 + ox] = (bf16_t)t[threadIdx.x][threadIdx.y + i];
}

// ---------------------------------------------------------------------------
__global__ void memfill(const float* __restrict__ m_k, const float* __restrict__ m_v,
                        bf16_t* __restrict__ Kbf, bf16_t* __restrict__ Vt)
{
    int tid = blockIdx.x * 256 + threadIdx.x;
    if (tid < 4 * 64 * 512) {
        int c  = tid & 511;
        int mi = (tid >> 9) & 63;
        int b  = tid >> 15;
        float v = (mi < MSL_) ? 8.0f * m_k[mi * 512 + c] : 0.0f;   // sqrt(DK)=8
        Kbf[((size_t)b * NKP_ + NK_ + mi) * 512 + c] = (bf16_t)v;
    } else {
        int t  = tid - 4 * 64 * 512;
        int mi = t & 63;
        int dv = (t >> 6) & 63;
        int h  = (t >> 12) & 7;
        int b  = t >> 15;
        float v = (mi < MSL_) ? 6.324555320336759f * m_v[mi * 512 + h * 64 + dv] : 0.0f; // sqrt(M)
        Vt[(((size_t)b * H_ + h) * 64 + dv) * NKP_ + NK_ + mi] = (bf16_t)v;
    }
}

// ---------------------------------------------------------------------------
// Shared GEMM core: C(8192x512) = A @ BT^T, epilogue (v+bias)*scale.
// ---------------------------------------------------------------------------
template<bool AF32>
__device__ __forceinline__ void gemm_core(
    bf16_t (*As)[72], bf16_t (*Bs)[72],
    const void* __restrict__ Av, const bf16_t* __restrict__ BT,
    const float* __restrict__ bias, void* __restrict__ dstv,
    int dstBS, int epi, float scale)
{
    const int tid = threadIdx.x;
    const int w = tid >> 6, l = tid & 63, lg = l >> 4, lr = l & 15;
    const int wr = w >> 1, wc = w & 1;
    const int blockM = blockIdx.x * 128, blockN = blockIdx.y * 128;

    f32x4 acc[4][4];
    const f32x4 zv = {0.f, 0.f, 0.f, 0.f};
#pragma unroll
    for (int i = 0; i < 4; i++)
#pragma unroll
        for (int j = 0; j < 4; j++) acc[i][j] = zv;

    const int ar = tid >> 1;
    const int ac = (tid & 1) * 32;

    for (int k0 = 0; k0 < 512; k0 += 64) {
        if (k0) __syncthreads();
        if constexpr (AF32) {
            const float* arow = (const float*)Av + (size_t)(blockM + ar) * 512 + k0 + ac;
#pragma unroll
            for (int i = 0; i < 8; i++) {
                float4 v = ((const float4*)arow)[i];
                bf16x4 pk = {(bf16_t)v.x, (bf16_t)v.y, (bf16_t)v.z, (bf16_t)v.w};
                *(bf16x4*)&As[ar][ac + i * 4] = pk;
            }
        } else {
            const bf16_t* arow = (const bf16_t*)Av + (size_t)(blockM + ar) * 512 + k0 + ac;
#pragma unroll
            for (int i = 0; i < 4; i++)
                *(uint4*)&As[ar][ac + i * 8] = ((const uint4*)arow)[i];
        }
        {
            const bf16_t* brow = BT + (size_t)(blockN + ar) * 512 + k0 + ac;
#pragma unroll
            for (int i = 0; i < 4; i++)
                *(uint4*)&Bs[ar][ac + i * 8] = ((const uint4*)brow)[i];
        }
        __syncthreads();
#pragma unroll
        for (int ks = 0; ks < 2; ks++) {
            bf16x8 af[4], bfr[4];
#pragma unroll
            for (int mi = 0; mi < 4; mi++)
                af[mi] = *(const bf16x8*)&As[wr * 64 + mi * 16 + lr][ks * 32 + lg * 8];
#pragma unroll
            for (int ni = 0; ni < 4; ni++)
                bfr[ni] = *(const bf16x8*)&Bs[wc * 64 + ni * 16 + lr][ks * 32 + lg * 8];
#pragma unroll
            for (int mi = 0; mi < 4; mi++)
#pragma unroll
                for (int ni = 0; ni < 4; ni++)
                    acc[mi][ni] = __builtin_amdgcn_mfma_f32_16x16x32_bf16(af[mi], bfr[ni], acc[mi][ni], 0, 0, 0);
        }
    }

    const int colbase = blockN + wc * 64;
    float bias_v[4];
#pragma unroll
    for (int ni = 0; ni < 4; ni++) bias_v[ni] = bias[colbase + ni * 16 + lr];

#pragma unroll
    for (int mi = 0; mi < 4; mi++) {
        const int r0 = blockM + wr * 64 + mi * 16 + lg * 4;
#pragma unroll
        for (int ni = 0; ni < 4; ni++) {
            const int c = colbase + ni * 16 + lr;
            f32x4 v = acc[mi][ni];
            if (epi == 2) {
                float* dst = (float*)dstv;
#pragma unroll
                for (int j = 0; j < 4; j++)
                    dst[(size_t)(r0 + j) * 512 + c] = (v[j] + bias_v[ni]) * scale;
            } else if (epi == 0) {
                bf16_t* dst = (bf16_t*)dstv;
#pragma unroll
                for (int j = 0; j < 4; j++) {
                    int rr = r0 + j;
                    int bb = rr >> 11, nn = rr & 2047;
                    dst[((size_t)bb * dstBS + nn) * 512 + c] = (bf16_t)((v[j] + bias_v[ni]) * scale);
                }
            } else {
                bf16_t* dst = (bf16_t*)dstv;
                int bb = r0 >> 11, n0 = r0 & 2047;
                int hh = c >> 6, dv = c & 63;
                bf16x4 pk;
#pragma unroll
                for (int j = 0; j < 4; j++) pk[j] = (bf16_t)((v[j] + bias_v[ni]) * scale);
                *(bf16x4*)(dst + (((size_t)bb * H_ + hh) * 64 + dv) * NKP_ + n0) = pk;
            }
        }
    }
}

__global__ __launch_bounds__(256) void gemm_qkv(
    const float* __restrict__ q, const float* __restrict__ k, const float* __restrict__ v,
    const bf16_t* __restrict__ WqT, const bf16_t* __restrict__ WkT, const bf16_t* __restrict__ WvT,
    const float* __restrict__ bq, const float* __restrict__ bk, const float* __restrict__ bv,
    bf16_t* __restrict__ Qbf, bf16_t* __restrict__ Kbf, bf16_t* __restrict__ Vt)
{
    __shared__ bf16_t As[128][72];
    __shared__ bf16_t Bs[128][72];
    const void* Av; const bf16_t* BT; const float* bias; void* dst;
    int dstBS, epi; float scale = 1.0f;
    switch (blockIdx.z) {
        case 0:  Av = q; BT = WqT; bias = bq; dst = Qbf; dstBS = 2048; epi = 0; scale = SCL2; break;
        case 1:  Av = k; BT = WkT; bias = bk; dst = Kbf; dstBS = NKP_; epi = 0; break;
        default: Av = v; BT = WvT; bias = bv; dst = Vt;  dstBS = 0;    epi = 1; break;
    }
    gemm_core<true>(As, Bs, Av, BT, bias, dst, dstBS, epi, scale);
}

__global__ __launch_bounds__(256) void gemm_fin(
    const bf16_t* __restrict__ Obuf, const bf16_t* __restrict__ WoT,
    const float* __restrict__ bo, float* __restrict__ out)
{
    __shared__ bf16_t As[128][72];
    __shared__ bf16_t Bs[128][72];
    gemm_core<false>(As, Bs, Obuf, WoT, bo, out, 0, 2, 1.0f);
}

// ---------------------------------------------------------------------------
// Fused flash attention — R15 4-buffer ring (17 barriers) with ALL VMEM
// HOISTED TO PERIOD TOP. The __syncthreads drain (implicit vmcnt(0)) retires
// every load issued in the period; R15 issued attw prefetches mid-period so
// each barrier exposed residual HBM latency. Now each period opens with
// {STAGE x2, PREFETCH(T+2)->spare, } then compute, with PREFETCH(T+3)
// into the just-freed cur0 after the first APPLY — every load gets >=1 tile
// (~600cy) and most get a full period (~1200cy) of compute cover. attw regs
// use a 3-way rotation (c0,c1,sp)->(sp,c0,c1); with the 2-cycle LDS ring the
// combined state cycles every 6 periods (15 main periods = 2x6 + 3).
// R16 lesson baked in: K/V must stay LDS-staged (register-direct = R3 regime).
// Pure __syncthreads (counted-vmcnt retired after R13's race).
// ---------------------------------------------------------------------------
template<bool BYTEM>
__global__ __launch_bounds__(512) void attn_fused(
    const bf16_t* __restrict__ Qbf, const bf16_t* __restrict__ Kbf,
    const bf16_t* __restrict__ Vt, const float* __restrict__ attw,
    const void* __restrict__ maskv, const int* __restrict__ mflag,
    bf16_t* __restrict__ Obuf)
{
    if ((*mflag != 0) != BYTEM) return;   // twin-variant dispatch on mask dtype

    __shared__ bf16_t Ks[4][64][64];      // 32 KB ring [buf][k-row][d]
    __shared__ bf16_t Vs[4][64][64];      // 32 KB ring [buf][dv-row][k]
    __shared__ bf16_t Pl[8][1024];        // 16 KB per-wave P crossing

    const int tid = threadIdx.x;
    const int wv = tid >> 6, l = tid & 63, lg = l >> 4, lr = l & 15;
    const int qt = blockIdx.x, h = blockIdx.y, b = blockIdx.z;
    const int q0w = qt * 128 + wv * 16;
    bf16_t* Pw = &Pl[wv][0];

    const size_t bh = (size_t)(b * H_ + h);
    const float* wbase = attw + bh * (size_t)NQ_ * NK_;
    const unsigned char* mb8 = (const unsigned char*)maskv + bh * (size_t)NQ_ * NK_;
    const int* mb32 = (const int*)maskv + bh * (size_t)NQ_ * NK_;
    const char* kbase8 = (const char*)(Kbf + (size_t)b * NKP_ * 512 + h * 64);
    const char* vbase8 = (const char*)(Vt + bh * 64 * (size_t)NKP_);

    // Q fragments (B-operand of S^T); Q pre-scaled by 0.125*log2(e)
    bf16x8 qf0 = *(const bf16x8*)&Qbf[((size_t)b * NQ_ + q0w + lr) * 512 + h * 64 + lg * 8];
    bf16x8 qf1 = *(const bf16x8*)&Qbf[((size_t)b * NQ_ + q0w + lr) * 512 + h * 64 + 32 + lg * 8];

    const f32x4 zv = {0.f, 0.f, 0.f, 0.f};
    f32x4 oacc[4];
#pragma unroll
    for (int i = 0; i < 4; i++) oacc[i] = zv;
    float lsum = 0.f;
    f32x4 sA[4];

    f32x4 wA[4], wB[4], wC[4];
    unsigned mA[4], mB[4], mC[4];          // byte-mask buffers
    unsigned miA[16], miB[16], miC[16];    // int32-mask buffers (dead if BYTEM)

    const int srow = l >> 3;                       // row within 8-row part
    const int scsw = ((l & 7) ^ (srow & 7)) * 16;  // swizzled 16B chunk offset

// 8 waves stage one 64x64 K tile + one 64x64 V tile; 2 gload_lds/wave
#define STAGE(BUF, KCB) do {                                                      \
    const int r_ = wv * 8 + srow;                                                 \
    GLOAD_LDS16(kbase8 + (size_t)((KCB) + r_) * 1024 + scsw,                      \
                (char*)&Ks[BUF][0][0] + wv * 1024);                               \
    GLOAD_LDS16(vbase8 + (size_t)r_ * 4224 + (size_t)(KCB) * 2 + scsw,            \
                (char*)&Vs[BUF][0][0] + wv * 1024);                               \
} while (0)

// 8 VMEM loads: 4x dwordx4 attw + 4x mask (dword or dwordx4)
#define PREFETCH(KT, WB_, MB_, MIB_) do {                                         \
    const float* wp_ = wbase + (size_t)(q0w + lr) * NK_ + (KT) * 64 + lg * 4;     \
    _Pragma("unroll") for (int n_ = 0; n_ < 4; n_++)                              \
        WB_[n_] = *(const f32x4*)(wp_ + n_ * 16);                                 \
    if constexpr (BYTEM) {                                                        \
        const unsigned char* mp_ = mb8 + (size_t)(q0w + lr) * NK_ + (KT) * 64 + lg * 4; \
        _Pragma("unroll") for (int n_ = 0; n_ < 4; n_++)                          \
            MB_[n_] = *(const unsigned*)(mp_ + n_ * 16);                          \
    } else {                                                                      \
        const int* mp_ = mb32 + (size_t)(q0w + lr) * NK_ + (KT) * 64 + lg * 4;    \
        _Pragma("unroll") for (int n_ = 0; n_ < 4; n_++) {                        \
            uint4 t_ = *(const uint4*)(mp_ + n_ * 16);                            \
            MIB_[n_ * 4 + 0] = t_.x; MIB_[n_ * 4 + 1] = t_.y;                     \
            MIB_[n_ * 4 + 2] = t_.z; MIB_[n_ * 4 + 3] = t_.w; }                   \
    }                                                                             \
} while (0)

#define QKT_LDS(BC) do {                                                          \
    const int sw_ = (lg ^ (lr & 7)) * 8;                                          \
    _Pragma("unroll") for (int n_ = 0; n_ < 4; n_++) {                            \
        const int kr_ = n_ * 16 + lr;                                             \
        f32x4 a_ = zv;                                                            \
        a_ = __builtin_amdgcn_mfma_f32_16x16x32_bf16(*(const bf16x8*)&Ks[BC][kr_][sw_], qf0, a_, 0, 0, 0); \
        a_ = __builtin_amdgcn_mfma_f32_16x16x32_bf16(*(const bf16x8*)&Ks[BC][kr_][sw_ ^ 32], qf1, a_, 0, 0, 0); \
        sA[n_] = a_;                                                              \
    }                                                                             \
} while (0)

#define APPLY(WB_, MB_, MIB_) do {                                                \
    _Pragma("unroll") for (int n_ = 0; n_ < 4; n_++)                              \
    _Pragma("unroll") for (int j_ = 0; j_ < 4; j_++) {                            \
        bool mk_;                                                                 \
        if constexpr (BYTEM) mk_ = ((MB_[n_] >> (8 * j_)) & 0xffu) != 0;          \
        else                 mk_ = (MIB_[n_ * 4 + j_] != 0);                      \
        sA[n_][j_] = mk_ ? -1e30f : sA[n_][j_] * WB_[n_][j_];                     \
    }                                                                             \
} while (0)

// max-free: P = exp2(s) raw; per-lane lsum; no per-tile cross-lane ops
#define SMPV(BC) do {                                                             \
    _Pragma("unroll") for (int n_ = 0; n_ < 4; n_++)                              \
    _Pragma("unroll") for (int j_ = 0; j_ < 4; j_++) {                            \
        float p_ = exp2f(sA[n_][j_]);                                             \
        sA[n_][j_] = p_; lsum += p_;                                              \
    }                                                                             \
    _Pragma("unroll") for (int n_ = 0; n_ < 4; n_++) {                            \
        int c_ = n_ * 2 + (lg >> 1);                                              \
        int qp_ = (lr + 4 * c_) & 15;                                             \
        bf16x4 pk_ = {(bf16_t)sA[n_][0], (bf16_t)sA[n_][1],                       \
                      (bf16_t)sA[n_][2], (bf16_t)sA[n_][3]};                      \
        *(bf16x4*)&Pw[c_ * 128 + qp_ * 8 + (lg & 1) * 4] = pk_;                   \
    }                                                                             \
    bf16x8 pf0_ = *(const bf16x8*)&Pw[lg * 128 + ((lr + 4 * lg) & 15) * 8];       \
    bf16x8 pf1_ = *(const bf16x8*)&Pw[(4 + lg) * 128 + ((lr + 4 * (4 + lg)) & 15) * 8]; \
    const int vsw_ = (lg ^ (lr & 7)) * 8;                                         \
    _Pragma("unroll") for (int n2_ = 0; n2_ < 4; n2_++) {                         \
        const int vr_ = n2_ * 16 + lr;                                            \
        oacc[n2_] = __builtin_amdgcn_mfma_f32_16x16x32_bf16(*(const bf16x8*)&Vs[BC][vr_][vsw_], pf0_, oacc[n2_], 0, 0, 0); \
        oacc[n2_] = __builtin_amdgcn_mfma_f32_16x16x32_bf16(*(const bf16x8*)&Vs[BC][vr_][vsw_ ^ 32], pf1_, oacc[n2_], 0, 0, 0); \
    }                                                                             \
} while (0)

#define SUBB(BC, W_, M_, MI_) do {                                                \
    QKT_LDS(BC); APPLY(W_, M_, MI_); SMPV(BC);                                    \
} while (0)

// period for tiles T,T+1: ALL VMEM at top (2 stages + attw(T+2)->spare),
// attw(T+3)->cur0 right after first APPLY frees it; one barrier at end.
#define PERIOD(T, B0, B1, S0, S1, C0,MC0,MIC0, C1,MC1,MIC1, SP,MSP,MISP) do {     \
    STAGE(S0, ((T) + 2) * 64);                                                    \
    STAGE(S1, ((T) + 3) * 64);                                                    \
    PREFETCH((T) + 2, SP, MSP, MISP);                                             \
    QKT_LDS(B0);                                                                  \
    APPLY(C0, MC0, MIC0);                                                         \
    PREFETCH((T) + 3, C0, MC0, MIC0);                                             \
    SMPV(B0);                                                                     \
    SUBB(B1, C1, MC1, MIC1);                                                      \
    __syncthreads();                                                              \
} while (0)

    // ---- prologue: stage memslot->b0, t0->b1, t1->b2; attw(0)->wA, (1)->wB ----
    STAGE(0, 2048);
    STAGE(1, 0);
    STAGE(2, 64);
    PREFETCH(0, wA, mA, miA);
    PREFETCH(1, wB, mB, miB);
    __syncthreads();

    // ---- memslot body (buf0) ----
    {
        QKT_LDS(0);
#pragma unroll
        for (int n_ = 0; n_ < 4; n_++)
#pragma unroll
            for (int j_ = 0; j_ < 4; j_++) {
                int kloc = n_ * 16 + lg * 4 + j_;
                sA[n_][j_] = (kloc >= MSL_) ? -1e30f : sA[n_][j_];
            }
        SMPV(0);
        __syncthreads();   // b0 free for reuse in period 0
    }

    // ---- 15 main periods (tiles 0..29); state cycle = 6 periods ----
    for (int t = 0; t < 24; t += 12) {
        PERIOD(t,      1, 2, 3, 0,  wA,mA,miA, wB,mB,miB, wC,mC,miC);
        PERIOD(t + 2,  3, 0, 1, 2,  wC,mC,miC, wA,mA,miA, wB,mB,miB);
        PERIOD(t + 4,  1, 2, 3, 0,  wB,mB,miB, wC,mC,miC, wA,mA,miA);
        PERIOD(t + 6,  3, 0, 1, 2,  wA,mA,miA, wB,mB,miB, wC,mC,miC);
        PERIOD(t + 8,  1, 2, 3, 0,  wC,mC,miC, wA,mA,miA, wB,mB,miB);
        PERIOD(t + 10, 3, 0, 1, 2,  wB,mB,miB, wC,mC,miC, wA,mA,miA);
    }
    PERIOD(24, 1, 2, 3, 0,  wA,mA,miA, wB,mB,miB, wC,mC,miC);
    PERIOD(26, 3, 0, 1, 2,  wC,mC,miC, wA,mA,miA, wB,mB,miB);
    PERIOD(28, 1, 2, 3, 0,  wB,mB,miB, wC,mC,miC, wA,mA,miA);
    // tail: tiles 30 (b3, attw in wA), 31 (b0, attw in wB); no staging
    SUBB(3, wA, mA, miA);
    SUBB(0, wB, mB, miB);

    // ---- epilogue: ONE lsum reduction, then normalize + store ----
    float ts = lsum;
    ts += __shfl_xor(ts, 16);
    ts += __shfl_xor(ts, 32);
    float invl = 1.0f / ts;
#pragma unroll
    for (int n2 = 0; n2 < 4; n2++) {
        bf16x4 ov = {(bf16_t)(oacc[n2][0] * invl), (bf16_t)(oacc[n2][1] * invl),
                     (bf16_t)(oacc[n2][2] * invl), (bf16_t)(oacc[n2][3] * invl)};
        *(bf16x4*)&Obuf[((size_t)b * NQ_ + q0w + lr) * 512 + h * 64 + n2 * 16 + lg * 4] = ov;
    }

#undef STAGE
#undef PREFETCH
#undef QKT_LDS
#undef APPLY
#undef SMPV
#undef SUBB
#undef PERIOD
}

// ---------------------------------------------------------------------------
extern "C" void kernel_launch(void* const* d_in, const int* in_sizes, int n_in,
                              void* d_out, int out_size, void* d_ws, size_t ws_size,
                              hipStream_t stream)
{
    const float* queries = (const float*)d_in[0];
    const float* keys    = (const float*)d_in[1];
    const float* values  = (const float*)d_in[2];
    const float* attw    = (const float*)d_in[3];
    const void*  maskv   = d_in[4];
    const float* Wq = (const float*)d_in[5];
    const float* bq = (const float*)d_in[6];
    const float* Wk = (const float*)d_in[7];
    const float* bk = (const float*)d_in[8];
    const float* Wv = (const float*)d_in[9];
    const float* bv = (const float*)d_in[10];
    const float* Wo = (const float*)d_in[11];
    const float* bo = (const float*)d_in[12];
    const float* m_k = (const float*)d_in[13];
    const float* m_v = (const float*)d_in[14];

    char* ws = (char*)d_ws;
    bf16_t* WqT  = (bf16_t*)(ws + 0);
    bf16_t* WkT  = (bf16_t*)(ws + 524288);
    bf16_t* WvT  = (bf16_t*)(ws + 1048576);
    bf16_t* WoT  = (bf16_t*)(ws + 1572864);
    bf16_t* Qbf  = (bf16_t*)(ws + 2097152);              // [4][2048][512]
    bf16_t* Kbf  = (bf16_t*)(ws + 10485760);             // [4][2112][512]
    bf16_t* Vt   = (bf16_t*)(ws + 19136512);             // [4][8][64][2112]
    bf16_t* Obuf = (bf16_t*)(ws + 27787264);             // [4][2048][512]
    int*    mflag = (int*)(ws + 36175872);

    detect_mask<<<1, 256, 0, stream>>>((const unsigned int*)maskv, mflag);
    transpose_convert4<<<dim3(16, 16, 4), dim3(32, 8), 0, stream>>>(
        Wq, Wk, Wv, Wo, WqT, WkT, WvT, WoT);
    memfill<<<1024, 256, 0, stream>>>(m_k, m_v, Kbf, Vt);

    gemm_qkv<<<dim3(64, 4, 3), 256, 0, stream>>>(
        queries, keys, values, WqT, WkT, WvT, bq, bk, bv, Qbf, Kbf, Vt);

    attn_fused<true><<<dim3(16, H_, B_), 512, 0, stream>>>(Qbf, Kbf, Vt, attw, maskv, mflag, Obuf);
    attn_fused<false><<<dim3(16, H_, B_), 512, 0, stream>>>(Qbf, Kbf, Vt, attw, maskv, mflag, Obuf);

    gemm_fin<<<dim3(64, 4), 256, 0, stream>>>(Obuf, WoT, bo, (float*)d_out);
    (void)in_sizes; (void)n_in; (void)out_size; (void)ws_size;
}

// Round 18
// 333.966 us; speedup vs baseline: 1.5027x; 1.0349x over previous
//
#include <hip/hip_runtime.h>
#include <hip/hip_bf16.h>
#include <cstdint>
#include <cstddef>

typedef __bf16 bf16_t;
typedef __bf16 bf16x8 __attribute__((ext_vector_type(8)));
typedef __bf16 bf16x4 __attribute__((ext_vector_type(4)));
typedef float  f32x4  __attribute__((ext_vector_type(4)));

#define B_    4
#define NQ_   2048
#define NK_   2048
#define H_    8
#define MSL_  40
#define NKP_  2112   // NK + 64 (memory slots padded)
#define SCL2  0.18033688011112042f   // 0.125 * log2(e), folded into Q projection

#define GLOAD_LDS16(GP, LP)                                                        \
    __builtin_amdgcn_global_load_lds(                                              \
        (const __attribute__((address_space(1))) unsigned int*)(GP),               \
        (__attribute__((address_space(3))) unsigned int*)(LP), 16, 0, 0)

// ---------------------------------------------------------------------------
__global__ void detect_mask(const unsigned int* __restrict__ m, int* __restrict__ flag)
{
    __shared__ int found;
    if (threadIdx.x == 0) found = 0;
    __syncthreads();
    unsigned int acc = 0;
    for (int i = threadIdx.x; i < 65536; i += 256)
        acc |= (m[i] & 0xFFFFFF00u);
    if (acc) found = 1;
    __syncthreads();
    if (threadIdx.x == 0) *flag = found;
}

// ---------------------------------------------------------------------------
__global__ void transpose_convert4(const float* __restrict__ s0, const float* __restrict__ s1,
                                   const float* __restrict__ s2, const float* __restrict__ s3,
                                   bf16_t* __restrict__ d0, bf16_t* __restrict__ d1,
                                   bf16_t* __restrict__ d2, bf16_t* __restrict__ d3)
{
    const float* src; bf16_t* dst;
    switch (blockIdx.z) {
        case 0:  src = s0; dst = d0; break;
        case 1:  src = s1; dst = d1; break;
        case 2:  src = s2; dst = d2; break;
        default: src = s3; dst = d3; break;
    }
    __shared__ float t[32][33];
    int x  = blockIdx.x * 32 + threadIdx.x;
    int y0 = blockIdx.y * 32 + threadIdx.y;
#pragma unroll
    for (int i = 0; i < 32; i += 8)
        t[threadIdx.y + i][threadIdx.x] = src[(size_t)(y0 + i) * 512 + x];
    __syncthreads();
    int ox  = blockIdx.y * 32 + threadIdx.x;
    int oy0 = blockIdx.x * 32 + threadIdx.y;
#pragma unroll
    for (int i = 0; i < 32; i += 8)
        dst[(size_t)(oy0 + i) * 512 + ox] = (bf16_t)t[threadIdx.x][threadIdx.y + i];
}

// ---------------------------------------------------------------------------
__global__ void memfill(const float* __restrict__ m_k, const float* __restrict__ m_v,
                        bf16_t* __restrict__ Kbf, bf16_t* __restrict__ Vt)
{
    int tid = blockIdx.x * 256 + threadIdx.x;
    if (tid < 4 * 64 * 512) {
        int c  = tid & 511;
        int mi = (tid >> 9) & 63;
        int b  = tid >> 15;
        float v = (mi < MSL_) ? 8.0f * m_k[mi * 512 + c] : 0.0f;   // sqrt(DK)=8
        Kbf[((size_t)b * NKP_ + NK_ + mi) * 512 + c] = (bf16_t)v;
    } else {
        int t  = tid - 4 * 64 * 512;
        int mi = t & 63;
        int dv = (t >> 6) & 63;
        int h  = (t >> 12) & 7;
        int b  = t >> 15;
        float v = (mi < MSL_) ? 6.324555320336759f * m_v[mi * 512 + h * 64 + dv] : 0.0f; // sqrt(M)
        Vt[(((size_t)b * H_ + h) * 64 + dv) * NKP_ + NK_ + mi] = (bf16_t)v;
    }
}

// ---------------------------------------------------------------------------
// Shared GEMM core, DOUBLE-BUFFERED LDS: C(8192x512) = A @ BT^T + bias, *scale.
// Per K-step: {sync; issue global loads(k+1)->regs; compute LDS[k&1] (32 MFMA
// of cover); write regs->LDS[(k+1)&1]}. 8 barriers/block instead of 16, and
// staging latency hides under the MFMA block — the same convoy fix proven on
// the attention kernel (R15). Safety: the top-of-iteration barrier guarantees
// all waves finished compute(k-1) — the last reader of the buffer being
// overwritten. LDS 72KB -> 2 blocks/CU.
// ---------------------------------------------------------------------------
template<bool AF32>
__device__ __forceinline__ void gemm_core(
    bf16_t (*As)[128][72], bf16_t (*Bs)[128][72],
    const void* __restrict__ Av, const bf16_t* __restrict__ BT,
    const float* __restrict__ bias, void* __restrict__ dstv,
    int dstBS, int epi, float scale)
{
    const int tid = threadIdx.x;
    const int w = tid >> 6, l = tid & 63, lg = l >> 4, lr = l & 15;
    const int wr = w >> 1, wc = w & 1;
    const int blockM = blockIdx.x * 128, blockN = blockIdx.y * 128;

    f32x4 acc[4][4];
    const f32x4 zv = {0.f, 0.f, 0.f, 0.f};
#pragma unroll
    for (int i = 0; i < 4; i++)
#pragma unroll
        for (int j = 0; j < 4; j++) acc[i][j] = zv;

    const int ar = tid >> 1;          // staged row 0..127
    const int ac = (tid & 1) * 32;    // staged col half

    float4 ra[8];      // A staging (f32 path)
    uint4  ra16[4];    // A staging (bf16 path)
    uint4  rb[4];      // B staging

#define GLOADT(K0) do {                                                           \
    if constexpr (AF32) {                                                         \
        const float* arow_ = (const float*)Av + (size_t)(blockM + ar) * 512 + (K0) + ac; \
        _Pragma("unroll") for (int i_ = 0; i_ < 8; i_++)                          \
            ra[i_] = ((const float4*)arow_)[i_];                                  \
    } else {                                                                      \
        const bf16_t* arow_ = (const bf16_t*)Av + (size_t)(blockM + ar) * 512 + (K0) + ac; \
        _Pragma("unroll") for (int i_ = 0; i_ < 4; i_++)                          \
            ra16[i_] = ((const uint4*)arow_)[i_];                                 \
    }                                                                             \
    const bf16_t* brow_ = BT + (size_t)(blockN + ar) * 512 + (K0) + ac;           \
    _Pragma("unroll") for (int i_ = 0; i_ < 4; i_++)                              \
        rb[i_] = ((const uint4*)brow_)[i_];                                       \
} while (0)

#define LDSWRITE(BUF) do {                                                        \
    if constexpr (AF32) {                                                         \
        _Pragma("unroll") for (int i_ = 0; i_ < 8; i_++) {                        \
            float4 v_ = ra[i_];                                                   \
            bf16x4 pk_ = {(bf16_t)v_.x, (bf16_t)v_.y, (bf16_t)v_.z, (bf16_t)v_.w}; \
            *(bf16x4*)&As[BUF][ar][ac + i_ * 4] = pk_;                            \
        }                                                                         \
    } else {                                                                      \
        _Pragma("unroll") for (int i_ = 0; i_ < 4; i_++)                          \
            *(uint4*)&As[BUF][ar][ac + i_ * 8] = ra16[i_];                        \
    }                                                                             \
    _Pragma("unroll") for (int i_ = 0; i_ < 4; i_++)                              \
        *(uint4*)&Bs[BUF][ar][ac + i_ * 8] = rb[i_];                              \
} while (0)

    // prologue: load + write k-tile 0 into buffer 0
    GLOADT(0);
    LDSWRITE(0);

    for (int kk = 0; kk < 8; kk++) {
        __syncthreads();
        if (kk < 7) GLOADT((kk + 1) * 64);
        const int cb = kk & 1;
#pragma unroll
        for (int ks = 0; ks < 2; ks++) {
            bf16x8 af[4], bfr[4];
#pragma unroll
            for (int mi = 0; mi < 4; mi++)
                af[mi] = *(const bf16x8*)&As[cb][wr * 64 + mi * 16 + lr][ks * 32 + lg * 8];
#pragma unroll
            for (int ni = 0; ni < 4; ni++)
                bfr[ni] = *(const bf16x8*)&Bs[cb][wc * 64 + ni * 16 + lr][ks * 32 + lg * 8];
#pragma unroll
            for (int mi = 0; mi < 4; mi++)
#pragma unroll
                for (int ni = 0; ni < 4; ni++)
                    acc[mi][ni] = __builtin_amdgcn_mfma_f32_16x16x32_bf16(af[mi], bfr[ni], acc[mi][ni], 0, 0, 0);
        }
        if (kk < 7) LDSWRITE(cb ^ 1);
    }

#undef GLOADT
#undef LDSWRITE

    const int colbase = blockN + wc * 64;
    float bias_v[4];
#pragma unroll
    for (int ni = 0; ni < 4; ni++) bias_v[ni] = bias[colbase + ni * 16 + lr];

#pragma unroll
    for (int mi = 0; mi < 4; mi++) {
        const int r0 = blockM + wr * 64 + mi * 16 + lg * 4;
#pragma unroll
        for (int ni = 0; ni < 4; ni++) {
            const int c = colbase + ni * 16 + lr;
            f32x4 v = acc[mi][ni];
            if (epi == 2) {
                float* dst = (float*)dstv;
#pragma unroll
                for (int j = 0; j < 4; j++)
                    dst[(size_t)(r0 + j) * 512 + c] = (v[j] + bias_v[ni]) * scale;
            } else if (epi == 0) {
                bf16_t* dst = (bf16_t*)dstv;
#pragma unroll
                for (int j = 0; j < 4; j++) {
                    int rr = r0 + j;
                    int bb = rr >> 11, nn = rr & 2047;
                    dst[((size_t)bb * dstBS + nn) * 512 + c] = (bf16_t)((v[j] + bias_v[ni]) * scale);
                }
            } else { // epi 1 : Vt[b][h][dv][n], pack 4 consecutive n
                bf16_t* dst = (bf16_t*)dstv;
                int bb = r0 >> 11, n0 = r0 & 2047;
                int hh = c >> 6, dv = c & 63;
                bf16x4 pk;
#pragma unroll
                for (int j = 0; j < 4; j++) pk[j] = (bf16_t)((v[j] + bias_v[ni]) * scale);
                *(bf16x4*)(dst + (((size_t)bb * H_ + hh) * 64 + dv) * NKP_ + n0) = pk;
            }
        }
    }
}

__global__ __launch_bounds__(256) void gemm_qkv(
    const float* __restrict__ q, const float* __restrict__ k, const float* __restrict__ v,
    const bf16_t* __restrict__ WqT, const bf16_t* __restrict__ WkT, const bf16_t* __restrict__ WvT,
    const float* __restrict__ bq, const float* __restrict__ bk, const float* __restrict__ bv,
    bf16_t* __restrict__ Qbf, bf16_t* __restrict__ Kbf, bf16_t* __restrict__ Vt)
{
    __shared__ bf16_t As[2][128][72];
    __shared__ bf16_t Bs[2][128][72];
    const void* Av; const bf16_t* BT; const float* bias; void* dst;
    int dstBS, epi; float scale = 1.0f;
    switch (blockIdx.z) {
        case 0:  Av = q; BT = WqT; bias = bq; dst = Qbf; dstBS = 2048; epi = 0; scale = SCL2; break;
        case 1:  Av = k; BT = WkT; bias = bk; dst = Kbf; dstBS = NKP_; epi = 0; break;
        default: Av = v; BT = WvT; bias = bv; dst = Vt;  dstBS = 0;    epi = 1; break;
    }
    gemm_core<true>(As, Bs, Av, BT, bias, dst, dstBS, epi, scale);
}

__global__ __launch_bounds__(256) void gemm_fin(
    const bf16_t* __restrict__ Obuf, const bf16_t* __restrict__ WoT,
    const float* __restrict__ bo, float* __restrict__ out)
{
    __shared__ bf16_t As[2][128][72];
    __shared__ bf16_t Bs[2][128][72];
    gemm_core<false>(As, Bs, Obuf, WoT, bo, out, 0, 2, 1.0f);
}

// ---------------------------------------------------------------------------
// Fused flash attention — R15 champion, byte-identical: 4-buffer LDS ring,
// 17 __syncthreads (2 tiles per period), max-free softmax, 8 waves/block,
// grid (16,8,4); LDS 80KB -> 2 blocks/CU. Tile t lives in buf (t+1)%4.
// ---------------------------------------------------------------------------
template<bool BYTEM>
__global__ __launch_bounds__(512) void attn_fused(
    const bf16_t* __restrict__ Qbf, const bf16_t* __restrict__ Kbf,
    const bf16_t* __restrict__ Vt, const float* __restrict__ attw,
    const void* __restrict__ maskv, const int* __restrict__ mflag,
    bf16_t* __restrict__ Obuf)
{
    if ((*mflag != 0) != BYTEM) return;   // twin-variant dispatch on mask dtype

    __shared__ bf16_t Ks[4][64][64];      // 32 KB ring [buf][k-row][d]
    __shared__ bf16_t Vs[4][64][64];      // 32 KB ring [buf][dv-row][k]
    __shared__ bf16_t Pl[8][1024];        // 16 KB per-wave P crossing

    const int tid = threadIdx.x;
    const int wv = tid >> 6, l = tid & 63, lg = l >> 4, lr = l & 15;
    const int qt = blockIdx.x, h = blockIdx.y, b = blockIdx.z;
    const int q0w = qt * 128 + wv * 16;
    bf16_t* Pw = &Pl[wv][0];

    const size_t bh = (size_t)(b * H_ + h);
    const float* wbase = attw + bh * (size_t)NQ_ * NK_;
    const unsigned char* mb8 = (const unsigned char*)maskv + bh * (size_t)NQ_ * NK_;
    const int* mb32 = (const int*)maskv + bh * (size_t)NQ_ * NK_;
    const char* kbase8 = (const char*)(Kbf + (size_t)b * NKP_ * 512 + h * 64);
    const char* vbase8 = (const char*)(Vt + bh * 64 * (size_t)NKP_);

    // Q fragments (B-operand of S^T); Q pre-scaled by 0.125*log2(e)
    bf16x8 qf0 = *(const bf16x8*)&Qbf[((size_t)b * NQ_ + q0w + lr) * 512 + h * 64 + lg * 8];
    bf16x8 qf1 = *(const bf16x8*)&Qbf[((size_t)b * NQ_ + q0w + lr) * 512 + h * 64 + 32 + lg * 8];

    const f32x4 zv = {0.f, 0.f, 0.f, 0.f};
    f32x4 oacc[4];
#pragma unroll
    for (int i = 0; i < 4; i++) oacc[i] = zv;
    float lsum = 0.f;
    f32x4 sA[4];

    f32x4 wA[4], wB[4];
    unsigned mA[4], mB[4];        // byte-mask buffers
    unsigned miA[16], miB[16];    // int32-mask buffers (dead if BYTEM)

    const int srow = l >> 3;                       // row within 8-row part
    const int scsw = ((l & 7) ^ (srow & 7)) * 16;  // swizzled 16B chunk offset

// 8 waves stage one 64x64 K tile + one 64x64 V tile; 2 gload_lds/wave
#define STAGE(BUF, KCB) do {                                                      \
    const int r_ = wv * 8 + srow;                                                 \
    GLOAD_LDS16(kbase8 + (size_t)((KCB) + r_) * 1024 + scsw,                      \
                (char*)&Ks[BUF][0][0] + wv * 1024);                               \
    GLOAD_LDS16(vbase8 + (size_t)r_ * 4224 + (size_t)(KCB) * 2 + scsw,            \
                (char*)&Vs[BUF][0][0] + wv * 1024);                               \
} while (0)

// 8 VMEM loads: 4x dwordx4 attw + 4x mask (dword or dwordx4)
#define PREFETCH(KT, WB_, MB_, MIB_) do {                                         \
    const float* wp_ = wbase + (size_t)(q0w + lr) * NK_ + (KT) * 64 + lg * 4;     \
    _Pragma("unroll") for (int n_ = 0; n_ < 4; n_++)                              \
        WB_[n_] = *(const f32x4*)(wp_ + n_ * 16);                                 \
    if constexpr (BYTEM) {                                                        \
        const unsigned char* mp_ = mb8 + (size_t)(q0w + lr) * NK_ + (KT) * 64 + lg * 4; \
        _Pragma("unroll") for (int n_ = 0; n_ < 4; n_++)                          \
            MB_[n_] = *(const unsigned*)(mp_ + n_ * 16);                          \
    } else {                                                                      \
        const int* mp_ = mb32 + (size_t)(q0w + lr) * NK_ + (KT) * 64 + lg * 4;    \
        _Pragma("unroll") for (int n_ = 0; n_ < 4; n_++) {                        \
            uint4 t_ = *(const uint4*)(mp_ + n_ * 16);                            \
            MIB_[n_ * 4 + 0] = t_.x; MIB_[n_ * 4 + 1] = t_.y;                     \
            MIB_[n_ * 4 + 2] = t_.z; MIB_[n_ * 4 + 3] = t_.w; }                   \
    }                                                                             \
} while (0)

#define QKT_LDS(BC) do {                                                          \
    const int sw_ = (lg ^ (lr & 7)) * 8;                                          \
    _Pragma("unroll") for (int n_ = 0; n_ < 4; n_++) {                            \
        const int kr_ = n_ * 16 + lr;                                             \
        f32x4 a_ = zv;                                                            \
        a_ = __builtin_amdgcn_mfma_f32_16x16x32_bf16(*(const bf16x8*)&Ks[BC][kr_][sw_], qf0, a_, 0, 0, 0); \
        a_ = __builtin_amdgcn_mfma_f32_16x16x32_bf16(*(const bf16x8*)&Ks[BC][kr_][sw_ ^ 32], qf1, a_, 0, 0, 0); \
        sA[n_] = a_;                                                              \
    }                                                                             \
} while (0)

#define APPLY(WB_, MB_, MIB_) do {                                                \
    _Pragma("unroll") for (int n_ = 0; n_ < 4; n_++)                              \
    _Pragma("unroll") for (int j_ = 0; j_ < 4; j_++) {                            \
        bool mk_;                                                                 \
        if constexpr (BYTEM) mk_ = ((MB_[n_] >> (8 * j_)) & 0xffu) != 0;          \
        else                 mk_ = (MIB_[n_ * 4 + j_] != 0);                      \
        sA[n_][j_] = mk_ ? -1e30f : sA[n_][j_] * WB_[n_][j_];                     \
    }                                                                             \
} while (0)

// max-free: P = exp2(s) raw; per-lane lsum; no per-tile cross-lane ops
#define SMPV(BC) do {                                                             \
    _Pragma("unroll") for (int n_ = 0; n_ < 4; n_++)                              \
    _Pragma("unroll") for (int j_ = 0; j_ < 4; j_++) {                            \
        float p_ = exp2f(sA[n_][j_]);                                             \
        sA[n_][j_] = p_; lsum += p_;                                              \
    }                                                                             \
    _Pragma("unroll") for (int n_ = 0; n_ < 4; n_++) {                            \
        int c_ = n_ * 2 + (lg >> 1);                                              \
        int qp_ = (lr + 4 * c_) & 15;                                             \
        bf16x4 pk_ = {(bf16_t)sA[n_][0], (bf16_t)sA[n_][1],                       \
                      (bf16_t)sA[n_][2], (bf16_t)sA[n_][3]};                      \
        *(bf16x4*)&Pw[c_ * 128 + qp_ * 8 + (lg & 1) * 4] = pk_;                   \
    }                                                                             \
    bf16x8 pf0_ = *(const bf16x8*)&Pw[lg * 128 + ((lr + 4 * lg) & 15) * 8];       \
    bf16x8 pf1_ = *(const bf16x8*)&Pw[(4 + lg) * 128 + ((lr + 4 * (4 + lg)) & 15) * 8]; \
    const int vsw_ = (lg ^ (lr & 7)) * 8;                                         \
    _Pragma("unroll") for (int n2_ = 0; n2_ < 4; n2_++) {                         \
        const int vr_ = n2_ * 16 + lr;                                            \
        oacc[n2_] = __builtin_amdgcn_mfma_f32_16x16x32_bf16(*(const bf16x8*)&Vs[BC][vr_][vsw_], pf0_, oacc[n2_], 0, 0, 0); \
        oacc[n2_] = __builtin_amdgcn_mfma_f32_16x16x32_bf16(*(const bf16x8*)&Vs[BC][vr_][vsw_ ^ 32], pf1_, oacc[n2_], 0, 0, 0); \
    }                                                                             \
} while (0)

// sub-body: tile T from ring buf BC; consume attw regs W_; refill W_ with
// attw(T+2) (2-deep, arrives before use — next period is 1+ barrier away)
#define SUBB(T, BC, W_, M_, MI_) do {                                            \
    QKT_LDS(BC);                                                                  \
    APPLY(W_, M_, MI_);                                                           \
    if ((T) < 30) PREFETCH((T) + 2, W_, M_, MI_);                                 \
    SMPV(BC);                                                                     \
} while (0)

// period: process tiles T (buf B0), T+1 (buf B1); stage T+2 -> S0, T+3 -> S1
#define PERIOD(T, B0, B1, S0, S1) do {                                            \
    if ((T) + 2 < 32) STAGE(S0, ((T) + 2) * 64);                                  \
    if ((T) + 3 < 32) STAGE(S1, ((T) + 3) * 64);                                  \
    SUBB((T),     B0, wA, mA, miA);                                               \
    SUBB((T) + 1, B1, wB, mB, miB);                                               \
    __syncthreads();                                                              \
} while (0)

    // ---- prologue: stage memslot->b0, t0->b1, t1->b2; attw(0)->wA ----
    STAGE(0, 2048);
    STAGE(1, 0);
    STAGE(2, 64);
    PREFETCH(0, wA, mA, miA);
    __syncthreads();

    // ---- memslot body (buf0); attw(1)->wB ----
    {
        QKT_LDS(0);
#pragma unroll
        for (int n_ = 0; n_ < 4; n_++)
#pragma unroll
            for (int j_ = 0; j_ < 4; j_++) {
                int kloc = n_ * 16 + lg * 4 + j_;
                sA[n_][j_] = (kloc >= MSL_) ? -1e30f : sA[n_][j_];
            }
        PREFETCH(1, wB, mB, miB);
        SMPV(0);
        __syncthreads();   // b0 free for reuse; t0/t1 staging drained
    }

    // ---- 8 periods of 4 tiles (2 periods each): tiles 0..31 ----
    for (int t = 0; t < 28; t += 4) {
        PERIOD(t,     1, 2, 3, 0);   // even period: read b1,b2; stage b3,b0
        PERIOD(t + 2, 3, 0, 1, 2);   // odd  period: read b3,b0; stage b1,b2
    }
    PERIOD(28, 1, 2, 3, 0);          // tiles 28,29; stage 30->b3, 31->b0
    // tail: tiles 30 (b3), 31 (b0); no staging
    SUBB(30, 3, wA, mA, miA);
    SUBB(31, 0, wB, mB, miB);

    // ---- epilogue: ONE lsum reduction, then normalize + store ----
    float ts = lsum;
    ts += __shfl_xor(ts, 16);
    ts += __shfl_xor(ts, 32);
    float invl = 1.0f / ts;
#pragma unroll
    for (int n2 = 0; n2 < 4; n2++) {
        bf16x4 ov = {(bf16_t)(oacc[n2][0] * invl), (bf16_t)(oacc[n2][1] * invl),
                     (bf16_t)(oacc[n2][2] * invl), (bf16_t)(oacc[n2][3] * invl)};
        *(bf16x4*)&Obuf[((size_t)b * NQ_ + q0w + lr) * 512 + h * 64 + n2 * 16 + lg * 4] = ov;
    }

#undef STAGE
#undef PREFETCH
#undef QKT_LDS
#undef APPLY
#undef SMPV
#undef SUBB
#undef PERIOD
}

// ---------------------------------------------------------------------------
extern "C" void kernel_launch(void* const* d_in, const int* in_sizes, int n_in,
                              void* d_out, int out_size, void* d_ws, size_t ws_size,
                              hipStream_t stream)
{
    const float* queries = (const float*)d_in[0];
    const float* keys    = (const float*)d_in[1];
    const float* values  = (const float*)d_in[2];
    const float* attw    = (const float*)d_in[3];
    const void*  maskv   = d_in[4];
    const float* Wq = (const float*)d_in[5];
    const float* bq = (const float*)d_in[6];
    const float* Wk = (const float*)d_in[7];
    const float* bk = (const float*)d_in[8];
    const float* Wv = (const float*)d_in[9];
    const float* bv = (const float*)d_in[10];
    const float* Wo = (const float*)d_in[11];
    const float* bo = (const float*)d_in[12];
    const float* m_k = (const float*)d_in[13];
    const float* m_v = (const float*)d_in[14];

    char* ws = (char*)d_ws;
    bf16_t* WqT  = (bf16_t*)(ws + 0);
    bf16_t* WkT  = (bf16_t*)(ws + 524288);
    bf16_t* WvT  = (bf16_t*)(ws + 1048576);
    bf16_t* WoT  = (bf16_t*)(ws + 1572864);
    bf16_t* Qbf  = (bf16_t*)(ws + 2097152);              // [4][2048][512]
    bf16_t* Kbf  = (bf16_t*)(ws + 10485760);             // [4][2112][512]
    bf16_t* Vt   = (bf16_t*)(ws + 19136512);             // [4][8][64][2112]
    bf16_t* Obuf = (bf16_t*)(ws + 27787264);             // [4][2048][512]
    int*    mflag = (int*)(ws + 36175872);

    detect_mask<<<1, 256, 0, stream>>>((const unsigned int*)maskv, mflag);
    transpose_convert4<<<dim3(16, 16, 4), dim3(32, 8), 0, stream>>>(
        Wq, Wk, Wv, Wo, WqT, WkT, WvT, WoT);
    memfill<<<1024, 256, 0, stream>>>(m_k, m_v, Kbf, Vt);

    gemm_qkv<<<dim3(64, 4, 3), 256, 0, stream>>>(
        queries, keys, values, WqT, WkT, WvT, bq, bk, bv, Qbf, Kbf, Vt);

    attn_fused<true><<<dim3(16, H_, B_), 512, 0, stream>>>(Qbf, Kbf, Vt, attw, maskv, mflag, Obuf);
    attn_fused<false><<<dim3(16, H_, B_), 512, 0, stream>>>(Qbf, Kbf, Vt, attw, maskv, mflag, Obuf);

    gemm_fin<<<dim3(64, 4), 256, 0, stream>>>(Obuf, WoT, bo, (float*)d_out);
    (void)in_sizes; (void)n_in; (void)out_size; (void)ws_size;
}

// Round 19
// 328.382 us; speedup vs baseline: 1.5283x; 1.0170x over previous
//
#include <hip/hip_runtime.h>
#include <hip/hip_bf16.h>
#include <cstdint>
#include <cstddef>

typedef __bf16 bf16_t;
typedef __bf16 bf16x8 __attribute__((ext_vector_type(8)));
typedef __bf16 bf16x4 __attribute__((ext_vector_type(4)));
typedef float  f32x4  __attribute__((ext_vector_type(4)));

#define B_    4
#define NQ_   2048
#define NK_   2048
#define H_    8
#define MSL_  40
#define NKP_  2112   // NK + 64 (memory slots padded)
#define SCL2  0.18033688011112042f   // 0.125 * log2(e), folded into Q projection

#define GLOAD_LDS16(GP, LP)                                                        \
    __builtin_amdgcn_global_load_lds(                                              \
        (const __attribute__((address_space(1))) unsigned int*)(GP),               \
        (__attribute__((address_space(3))) unsigned int*)(LP), 16, 0, 0)

// ---------------------------------------------------------------------------
// Fused setup: blocks 0..1023 transpose W* (f32->bf16, rows=n); blocks
// 1024..2047 fill memory-slot rows of Kbf / cols of Vt; block 2048 detects
// the mask element size (1=byte bool, 0=int32). All three are independent;
// fusing removes two stream-serialization points.
// ---------------------------------------------------------------------------
__global__ __launch_bounds__(256) void setup_fused(
    const float* __restrict__ Wq, const float* __restrict__ Wk,
    const float* __restrict__ Wv, const float* __restrict__ Wo,
    bf16_t* __restrict__ WqT, bf16_t* __restrict__ WkT,
    bf16_t* __restrict__ WvT, bf16_t* __restrict__ WoT,
    const float* __restrict__ m_k, const float* __restrict__ m_v,
    bf16_t* __restrict__ Kbf, bf16_t* __restrict__ Vt,
    const unsigned int* __restrict__ maskw, int* __restrict__ flag)
{
    __shared__ float t[32][33];
    __shared__ int found;
    const int blk = blockIdx.x;
    const int tid = threadIdx.x;

    if (blk < 1024) {
        // ---- transpose+convert: W (512x512 f32, rows=k) -> WT (bf16, rows=n)
        const int bz = blk >> 8, by = (blk >> 4) & 15, bx = blk & 15;
        const float* src; bf16_t* dst;
        switch (bz) {
            case 0:  src = Wq; dst = WqT; break;
            case 1:  src = Wk; dst = WkT; break;
            case 2:  src = Wv; dst = WvT; break;
            default: src = Wo; dst = WoT; break;
        }
        const int tx = tid & 31, ty = tid >> 5;     // (32,8)
        const int x  = bx * 32 + tx;
        const int y0 = by * 32 + ty;
#pragma unroll
        for (int i = 0; i < 32; i += 8)
            t[ty + i][tx] = src[(size_t)(y0 + i) * 512 + x];
        __syncthreads();
        const int ox  = by * 32 + tx;
        const int oy0 = bx * 32 + ty;
#pragma unroll
        for (int i = 0; i < 32; i += 8)
            dst[(size_t)(oy0 + i) * 512 + ox] = (bf16_t)t[tx][ty + i];
    } else if (blk < 2048) {
        // ---- memfill: memory-slot rows of Kbf, memory-slot cols of Vt ----
        int tt = (blk - 1024) * 256 + tid;
        if (tt < 4 * 64 * 512) {
            int c  = tt & 511;
            int mi = (tt >> 9) & 63;
            int b  = tt >> 15;
            float v = (mi < MSL_) ? 8.0f * m_k[mi * 512 + c] : 0.0f;   // sqrt(DK)=8
            Kbf[((size_t)b * NKP_ + NK_ + mi) * 512 + c] = (bf16_t)v;
        } else {
            int t2 = tt - 4 * 64 * 512;
            int mi = t2 & 63;
            int dv = (t2 >> 6) & 63;
            int h  = (t2 >> 12) & 7;
            int b  = t2 >> 15;
            float v = (mi < MSL_) ? 6.324555320336759f * m_v[mi * 512 + h * 64 + dv] : 0.0f; // sqrt(M)
            Vt[(((size_t)b * H_ + h) * 64 + dv) * NKP_ + NK_ + mi] = (bf16_t)v;
        }
    } else {
        // ---- detect mask dtype: byte bool -> high bytes nonzero somewhere
        if (tid == 0) found = 0;
        __syncthreads();
        unsigned int acc = 0;
        for (int i = tid; i < 65536; i += 256)
            acc |= (maskw[i] & 0xFFFFFF00u);
        if (acc) found = 1;
        __syncthreads();
        if (tid == 0) *flag = found;
    }
}

// ---------------------------------------------------------------------------
// Shared GEMM core, DOUBLE-BUFFERED LDS (R18): C = A @ BT^T + bias, *scale.
// ---------------------------------------------------------------------------
template<bool AF32>
__device__ __forceinline__ void gemm_core(
    bf16_t (*As)[128][72], bf16_t (*Bs)[128][72],
    const void* __restrict__ Av, const bf16_t* __restrict__ BT,
    const float* __restrict__ bias, void* __restrict__ dstv,
    int dstBS, int epi, float scale)
{
    const int tid = threadIdx.x;
    const int w = tid >> 6, l = tid & 63, lg = l >> 4, lr = l & 15;
    const int wr = w >> 1, wc = w & 1;
    const int blockM = blockIdx.x * 128, blockN = blockIdx.y * 128;

    f32x4 acc[4][4];
    const f32x4 zv = {0.f, 0.f, 0.f, 0.f};
#pragma unroll
    for (int i = 0; i < 4; i++)
#pragma unroll
        for (int j = 0; j < 4; j++) acc[i][j] = zv;

    const int ar = tid >> 1;          // staged row 0..127
    const int ac = (tid & 1) * 32;    // staged col half

    float4 ra[8];      // A staging (f32 path)
    uint4  ra16[4];    // A staging (bf16 path)
    uint4  rb[4];      // B staging

#define GLOADT(K0) do {                                                           \
    if constexpr (AF32) {                                                         \
        const float* arow_ = (const float*)Av + (size_t)(blockM + ar) * 512 + (K0) + ac; \
        _Pragma("unroll") for (int i_ = 0; i_ < 8; i_++)                          \
            ra[i_] = ((const float4*)arow_)[i_];                                  \
    } else {                                                                      \
        const bf16_t* arow_ = (const bf16_t*)Av + (size_t)(blockM + ar) * 512 + (K0) + ac; \
        _Pragma("unroll") for (int i_ = 0; i_ < 4; i_++)                          \
            ra16[i_] = ((const uint4*)arow_)[i_];                                 \
    }                                                                             \
    const bf16_t* brow_ = BT + (size_t)(blockN + ar) * 512 + (K0) + ac;           \
    _Pragma("unroll") for (int i_ = 0; i_ < 4; i_++)                              \
        rb[i_] = ((const uint4*)brow_)[i_];                                       \
} while (0)

#define LDSWRITE(BUF) do {                                                        \
    if constexpr (AF32) {                                                         \
        _Pragma("unroll") for (int i_ = 0; i_ < 8; i_++) {                        \
            float4 v_ = ra[i_];                                                   \
            bf16x4 pk_ = {(bf16_t)v_.x, (bf16_t)v_.y, (bf16_t)v_.z, (bf16_t)v_.w}; \
            *(bf16x4*)&As[BUF][ar][ac + i_ * 4] = pk_;                            \
        }                                                                         \
    } else {                                                                      \
        _Pragma("unroll") for (int i_ = 0; i_ < 4; i_++)                          \
            *(uint4*)&As[BUF][ar][ac + i_ * 8] = ra16[i_];                        \
    }                                                                             \
    _Pragma("unroll") for (int i_ = 0; i_ < 4; i_++)                              \
        *(uint4*)&Bs[BUF][ar][ac + i_ * 8] = rb[i_];                              \
} while (0)

    // prologue: load + write k-tile 0 into buffer 0
    GLOADT(0);
    LDSWRITE(0);

    for (int kk = 0; kk < 8; kk++) {
        __syncthreads();
        if (kk < 7) GLOADT((kk + 1) * 64);
        const int cb = kk & 1;
#pragma unroll
        for (int ks = 0; ks < 2; ks++) {
            bf16x8 af[4], bfr[4];
#pragma unroll
            for (int mi = 0; mi < 4; mi++)
                af[mi] = *(const bf16x8*)&As[cb][wr * 64 + mi * 16 + lr][ks * 32 + lg * 8];
#pragma unroll
            for (int ni = 0; ni < 4; ni++)
                bfr[ni] = *(const bf16x8*)&Bs[cb][wc * 64 + ni * 16 + lr][ks * 32 + lg * 8];
#pragma unroll
            for (int mi = 0; mi < 4; mi++)
#pragma unroll
                for (int ni = 0; ni < 4; ni++)
                    acc[mi][ni] = __builtin_amdgcn_mfma_f32_16x16x32_bf16(af[mi], bfr[ni], acc[mi][ni], 0, 0, 0);
        }
        if (kk < 7) LDSWRITE(cb ^ 1);
    }

#undef GLOADT
#undef LDSWRITE

    const int colbase = blockN + wc * 64;
    float bias_v[4];
#pragma unroll
    for (int ni = 0; ni < 4; ni++) bias_v[ni] = bias[colbase + ni * 16 + lr];

#pragma unroll
    for (int mi = 0; mi < 4; mi++) {
        const int r0 = blockM + wr * 64 + mi * 16 + lg * 4;
#pragma unroll
        for (int ni = 0; ni < 4; ni++) {
            const int c = colbase + ni * 16 + lr;
            f32x4 v = acc[mi][ni];
            if (epi == 2) {
                float* dst = (float*)dstv;
#pragma unroll
                for (int j = 0; j < 4; j++)
                    dst[(size_t)(r0 + j) * 512 + c] = (v[j] + bias_v[ni]) * scale;
            } else if (epi == 0) {
                bf16_t* dst = (bf16_t*)dstv;
#pragma unroll
                for (int j = 0; j < 4; j++) {
                    int rr = r0 + j;
                    int bb = rr >> 11, nn = rr & 2047;
                    dst[((size_t)bb * dstBS + nn) * 512 + c] = (bf16_t)((v[j] + bias_v[ni]) * scale);
                }
            } else { // epi 1 : Vt[b][h][dv][n], pack 4 consecutive n
                bf16_t* dst = (bf16_t*)dstv;
                int bb = r0 >> 11, n0 = r0 & 2047;
                int hh = c >> 6, dv = c & 63;
                bf16x4 pk;
#pragma unroll
                for (int j = 0; j < 4; j++) pk[j] = (bf16_t)((v[j] + bias_v[ni]) * scale);
                *(bf16x4*)(dst + (((size_t)bb * H_ + hh) * 64 + dv) * NKP_ + n0) = pk;
            }
        }
    }
}

__global__ __launch_bounds__(256) void gemm_qkv(
    const float* __restrict__ q, const float* __restrict__ k, const float* __restrict__ v,
    const bf16_t* __restrict__ WqT, const bf16_t* __restrict__ WkT, const bf16_t* __restrict__ WvT,
    const float* __restrict__ bq, const float* __restrict__ bk, const float* __restrict__ bv,
    bf16_t* __restrict__ Qbf, bf16_t* __restrict__ Kbf, bf16_t* __restrict__ Vt)
{
    __shared__ bf16_t As[2][128][72];
    __shared__ bf16_t Bs[2][128][72];
    const void* Av; const bf16_t* BT; const float* bias; void* dst;
    int dstBS, epi; float scale = 1.0f;
    switch (blockIdx.z) {
        case 0:  Av = q; BT = WqT; bias = bq; dst = Qbf; dstBS = 2048; epi = 0; scale = SCL2; break;
        case 1:  Av = k; BT = WkT; bias = bk; dst = Kbf; dstBS = NKP_; epi = 0; break;
        default: Av = v; BT = WvT; bias = bv; dst = Vt;  dstBS = 0;    epi = 1; break;
    }
    gemm_core<true>(As, Bs, Av, BT, bias, dst, dstBS, epi, scale);
}

__global__ __launch_bounds__(256) void gemm_fin(
    const bf16_t* __restrict__ Obuf, const bf16_t* __restrict__ WoT,
    const float* __restrict__ bo, float* __restrict__ out)
{
    __shared__ bf16_t As[2][128][72];
    __shared__ bf16_t Bs[2][128][72];
    gemm_core<false>(As, Bs, Obuf, WoT, bo, out, 0, 2, 1.0f);
}

// ---------------------------------------------------------------------------
// Fused flash attention — R15 champion, byte-identical: 4-buffer LDS ring,
// 17 __syncthreads (2 tiles per period), max-free softmax, 8 waves/block,
// grid (16,8,4); LDS 80KB -> 2 blocks/CU. Tile t lives in buf (t+1)%4.
// ---------------------------------------------------------------------------
template<bool BYTEM>
__global__ __launch_bounds__(512) void attn_fused(
    const bf16_t* __restrict__ Qbf, const bf16_t* __restrict__ Kbf,
    const bf16_t* __restrict__ Vt, const float* __restrict__ attw,
    const void* __restrict__ maskv, const int* __restrict__ mflag,
    bf16_t* __restrict__ Obuf)
{
    if ((*mflag != 0) != BYTEM) return;   // twin-variant dispatch on mask dtype

    __shared__ bf16_t Ks[4][64][64];      // 32 KB ring [buf][k-row][d]
    __shared__ bf16_t Vs[4][64][64];      // 32 KB ring [buf][dv-row][k]
    __shared__ bf16_t Pl[8][1024];        // 16 KB per-wave P crossing

    const int tid = threadIdx.x;
    const int wv = tid >> 6, l = tid & 63, lg = l >> 4, lr = l & 15;
    const int qt = blockIdx.x, h = blockIdx.y, b = blockIdx.z;
    const int q0w = qt * 128 + wv * 16;
    bf16_t* Pw = &Pl[wv][0];

    const size_t bh = (size_t)(b * H_ + h);
    const float* wbase = attw + bh * (size_t)NQ_ * NK_;
    const unsigned char* mb8 = (const unsigned char*)maskv + bh * (size_t)NQ_ * NK_;
    const int* mb32 = (const int*)maskv + bh * (size_t)NQ_ * NK_;
    const char* kbase8 = (const char*)(Kbf + (size_t)b * NKP_ * 512 + h * 64);
    const char* vbase8 = (const char*)(Vt + bh * 64 * (size_t)NKP_);

    // Q fragments (B-operand of S^T); Q pre-scaled by 0.125*log2(e)
    bf16x8 qf0 = *(const bf16x8*)&Qbf[((size_t)b * NQ_ + q0w + lr) * 512 + h * 64 + lg * 8];
    bf16x8 qf1 = *(const bf16x8*)&Qbf[((size_t)b * NQ_ + q0w + lr) * 512 + h * 64 + 32 + lg * 8];

    const f32x4 zv = {0.f, 0.f, 0.f, 0.f};
    f32x4 oacc[4];
#pragma unroll
    for (int i = 0; i < 4; i++) oacc[i] = zv;
    float lsum = 0.f;
    f32x4 sA[4];

    f32x4 wA[4], wB[4];
    unsigned mA[4], mB[4];        // byte-mask buffers
    unsigned miA[16], miB[16];    // int32-mask buffers (dead if BYTEM)

    const int srow = l >> 3;                       // row within 8-row part
    const int scsw = ((l & 7) ^ (srow & 7)) * 16;  // swizzled 16B chunk offset

// 8 waves stage one 64x64 K tile + one 64x64 V tile; 2 gload_lds/wave
#define STAGE(BUF, KCB) do {                                                      \
    const int r_ = wv * 8 + srow;                                                 \
    GLOAD_LDS16(kbase8 + (size_t)((KCB) + r_) * 1024 + scsw,                      \
                (char*)&Ks[BUF][0][0] + wv * 1024);                               \
    GLOAD_LDS16(vbase8 + (size_t)r_ * 4224 + (size_t)(KCB) * 2 + scsw,            \
                (char*)&Vs[BUF][0][0] + wv * 1024);                               \
} while (0)

// 8 VMEM loads: 4x dwordx4 attw + 4x mask (dword or dwordx4)
#define PREFETCH(KT, WB_, MB_, MIB_) do {                                         \
    const float* wp_ = wbase + (size_t)(q0w + lr) * NK_ + (KT) * 64 + lg * 4;     \
    _Pragma("unroll") for (int n_ = 0; n_ < 4; n_++)                              \
        WB_[n_] = *(const f32x4*)(wp_ + n_ * 16);                                 \
    if constexpr (BYTEM) {                                                        \
        const unsigned char* mp_ = mb8 + (size_t)(q0w + lr) * NK_ + (KT) * 64 + lg * 4; \
        _Pragma("unroll") for (int n_ = 0; n_ < 4; n_++)                          \
            MB_[n_] = *(const unsigned*)(mp_ + n_ * 16);                          \
    } else {                                                                      \
        const int* mp_ = mb32 + (size_t)(q0w + lr) * NK_ + (KT) * 64 + lg * 4;    \
        _Pragma("unroll") for (int n_ = 0; n_ < 4; n_++) {                        \
            uint4 t_ = *(const uint4*)(mp_ + n_ * 16);                            \
            MIB_[n_ * 4 + 0] = t_.x; MIB_[n_ * 4 + 1] = t_.y;                     \
            MIB_[n_ * 4 + 2] = t_.z; MIB_[n_ * 4 + 3] = t_.w; }                   \
    }                                                                             \
} while (0)

#define QKT_LDS(BC) do {                                                          \
    const int sw_ = (lg ^ (lr & 7)) * 8;                                          \
    _Pragma("unroll") for (int n_ = 0; n_ < 4; n_++) {                            \
        const int kr_ = n_ * 16 + lr;                                             \
        f32x4 a_ = zv;                                                            \
        a_ = __builtin_amdgcn_mfma_f32_16x16x32_bf16(*(const bf16x8*)&Ks[BC][kr_][sw_], qf0, a_, 0, 0, 0); \
        a_ = __builtin_amdgcn_mfma_f32_16x16x32_bf16(*(const bf16x8*)&Ks[BC][kr_][sw_ ^ 32], qf1, a_, 0, 0, 0); \
        sA[n_] = a_;                                                              \
    }                                                                             \
} while (0)

#define APPLY(WB_, MB_, MIB_) do {                                                \
    _Pragma("unroll") for (int n_ = 0; n_ < 4; n_++)                              \
    _Pragma("unroll") for (int j_ = 0; j_ < 4; j_++) {                            \
        bool mk_;                                                                 \
        if constexpr (BYTEM) mk_ = ((MB_[n_] >> (8 * j_)) & 0xffu) != 0;          \
        else                 mk_ = (MIB_[n_ * 4 + j_] != 0);                      \
        sA[n_][j_] = mk_ ? -1e30f : sA[n_][j_] * WB_[n_][j_];                     \
    }                                                                             \
} while (0)

// max-free: P = exp2(s) raw; per-lane lsum; no per-tile cross-lane ops
#define SMPV(BC) do {                                                             \
    _Pragma("unroll") for (int n_ = 0; n_ < 4; n_++)                              \
    _Pragma("unroll") for (int j_ = 0; j_ < 4; j_++) {                            \
        float p_ = exp2f(sA[n_][j_]);                                             \
        sA[n_][j_] = p_; lsum += p_;                                              \
    }                                                                             \
    _Pragma("unroll") for (int n_ = 0; n_ < 4; n_++) {                            \
        int c_ = n_ * 2 + (lg >> 1);                                              \
        int qp_ = (lr + 4 * c_) & 15;                                             \
        bf16x4 pk_ = {(bf16_t)sA[n_][0], (bf16_t)sA[n_][1],                       \
                      (bf16_t)sA[n_][2], (bf16_t)sA[n_][3]};                      \
        *(bf16x4*)&Pw[c_ * 128 + qp_ * 8 + (lg & 1) * 4] = pk_;                   \
    }                                                                             \
    bf16x8 pf0_ = *(const bf16x8*)&Pw[lg * 128 + ((lr + 4 * lg) & 15) * 8];       \
    bf16x8 pf1_ = *(const bf16x8*)&Pw[(4 + lg) * 128 + ((lr + 4 * (4 + lg)) & 15) * 8]; \
    const int vsw_ = (lg ^ (lr & 7)) * 8;                                         \
    _Pragma("unroll") for (int n2_ = 0; n2_ < 4; n2_++) {                         \
        const int vr_ = n2_ * 16 + lr;                                            \
        oacc[n2_] = __builtin_amdgcn_mfma_f32_16x16x32_bf16(*(const bf16x8*)&Vs[BC][vr_][vsw_], pf0_, oacc[n2_], 0, 0, 0); \
        oacc[n2_] = __builtin_amdgcn_mfma_f32_16x16x32_bf16(*(const bf16x8*)&Vs[BC][vr_][vsw_ ^ 32], pf1_, oacc[n2_], 0, 0, 0); \
    }                                                                             \
} while (0)

// sub-body: tile T from ring buf BC; consume attw regs W_; refill W_ with
// attw(T+2) (2-deep, arrives before use — next period is 1+ barrier away)
#define SUBB(T, BC, W_, M_, MI_) do {                                            \
    QKT_LDS(BC);                                                                  \
    APPLY(W_, M_, MI_);                                                           \
    if ((T) < 30) PREFETCH((T) + 2, W_, M_, MI_);                                 \
    SMPV(BC);                                                                     \
} while (0)

// period: process tiles T (buf B0), T+1 (buf B1); stage T+2 -> S0, T+3 -> S1
#define PERIOD(T, B0, B1, S0, S1) do {                                            \
    if ((T) + 2 < 32) STAGE(S0, ((T) + 2) * 64);                                  \
    if ((T) + 3 < 32) STAGE(S1, ((T) + 3) * 64);                                  \
    SUBB((T),     B0, wA, mA, miA);                                               \
    SUBB((T) + 1, B1, wB, mB, miB);                                               \
    __syncthreads();                                                              \
} while (0)

    // ---- prologue: stage memslot->b0, t0->b1, t1->b2; attw(0)->wA ----
    STAGE(0, 2048);
    STAGE(1, 0);
    STAGE(2, 64);
    PREFETCH(0, wA, mA, miA);
    __syncthreads();

    // ---- memslot body (buf0); attw(1)->wB ----
    {
        QKT_LDS(0);
#pragma unroll
        for (int n_ = 0; n_ < 4; n_++)
#pragma unroll
            for (int j_ = 0; j_ < 4; j_++) {
                int kloc = n_ * 16 + lg * 4 + j_;
                sA[n_][j_] = (kloc >= MSL_) ? -1e30f : sA[n_][j_];
            }
        PREFETCH(1, wB, mB, miB);
        SMPV(0);
        __syncthreads();   // b0 free for reuse; t0/t1 staging drained
    }

    // ---- 8 periods of 4 tiles (2 periods each): tiles 0..31 ----
    for (int t = 0; t < 28; t += 4) {
        PERIOD(t,     1, 2, 3, 0);   // even period: read b1,b2; stage b3,b0
        PERIOD(t + 2, 3, 0, 1, 2);   // odd  period: read b3,b0; stage b1,b2
    }
    PERIOD(28, 1, 2, 3, 0);          // tiles 28,29; stage 30->b3, 31->b0
    // tail: tiles 30 (b3), 31 (b0); no staging
    SUBB(30, 3, wA, mA, miA);
    SUBB(31, 0, wB, mB, miB);

    // ---- epilogue: ONE lsum reduction, then normalize + store ----
    float ts = lsum;
    ts += __shfl_xor(ts, 16);
    ts += __shfl_xor(ts, 32);
    float invl = 1.0f / ts;
#pragma unroll
    for (int n2 = 0; n2 < 4; n2++) {
        bf16x4 ov = {(bf16_t)(oacc[n2][0] * invl), (bf16_t)(oacc[n2][1] * invl),
                     (bf16_t)(oacc[n2][2] * invl), (bf16_t)(oacc[n2][3] * invl)};
        *(bf16x4*)&Obuf[((size_t)b * NQ_ + q0w + lr) * 512 + h * 64 + n2 * 16 + lg * 4] = ov;
    }

#undef STAGE
#undef PREFETCH
#undef QKT_LDS
#undef APPLY
#undef SMPV
#undef SUBB
#undef PERIOD
}

// ---------------------------------------------------------------------------
extern "C" void kernel_launch(void* const* d_in, const int* in_sizes, int n_in,
                              void* d_out, int out_size, void* d_ws, size_t ws_size,
                              hipStream_t stream)
{
    const float* queries = (const float*)d_in[0];
    const float* keys    = (const float*)d_in[1];
    const float* values  = (const float*)d_in[2];
    const float* attw    = (const float*)d_in[3];
    const void*  maskv   = d_in[4];
    const float* Wq = (const float*)d_in[5];
    const float* bq = (const float*)d_in[6];
    const float* Wk = (const float*)d_in[7];
    const float* bk = (const float*)d_in[8];
    const float* Wv = (const float*)d_in[9];
    const float* bv = (const float*)d_in[10];
    const float* Wo = (const float*)d_in[11];
    const float* bo = (const float*)d_in[12];
    const float* m_k = (const float*)d_in[13];
    const float* m_v = (const float*)d_in[14];

    char* ws = (char*)d_ws;
    bf16_t* WqT  = (bf16_t*)(ws + 0);
    bf16_t* WkT  = (bf16_t*)(ws + 524288);
    bf16_t* WvT  = (bf16_t*)(ws + 1048576);
    bf16_t* WoT  = (bf16_t*)(ws + 1572864);
    bf16_t* Qbf  = (bf16_t*)(ws + 2097152);              // [4][2048][512]
    bf16_t* Kbf  = (bf16_t*)(ws + 10485760);             // [4][2112][512]
    bf16_t* Vt   = (bf16_t*)(ws + 19136512);             // [4][8][64][2112]
    bf16_t* Obuf = (bf16_t*)(ws + 27787264);             // [4][2048][512]
    int*    mflag = (int*)(ws + 36175872);

    setup_fused<<<2049, 256, 0, stream>>>(
        Wq, Wk, Wv, Wo, WqT, WkT, WvT, WoT,
        m_k, m_v, Kbf, Vt, (const unsigned int*)maskv, mflag);

    gemm_qkv<<<dim3(64, 4, 3), 256, 0, stream>>>(
        queries, keys, values, WqT, WkT, WvT, bq, bk, bv, Qbf, Kbf, Vt);

    attn_fused<true><<<dim3(16, H_, B_), 512, 0, stream>>>(Qbf, Kbf, Vt, attw, maskv, mflag, Obuf);
    attn_fused<false><<<dim3(16, H_, B_), 512, 0, stream>>>(Qbf, Kbf, Vt, attw, maskv, mflag, Obuf);

    gemm_fin<<<dim3(64, 4), 256, 0, stream>>>(Obuf, WoT, bo, (float*)d_out);
    (void)in_sizes; (void)n_in; (void)out_size; (void)ws_size;
}